// Round 4
// baseline (238.040 us; speedup 1.0000x reference)
//
#include <hip/hip_runtime.h>
#include <hip/hip_bf16.h>
#include <math.h>

// Problem sizes (fixed by reference): B=256, M=64, N=32, D=128, T=64, L=128
#define B_ 256
#define M_ 64
#define N_ 32
#define D_ 128
#define T_ 64
#define L_ 128

typedef __attribute__((ext_vector_type(8))) short short8;   // 8 bf16 = 4 VGPRs (MFMA A/B frag)
typedef __attribute__((ext_vector_type(4))) float floatx4;  // MFMA C/D frag

__device__ __forceinline__ unsigned short f2bf(float f) {
  unsigned int u = __float_as_uint(f);
  unsigned int r = (u + 0x7fffu + ((u >> 16) & 1u)) >> 16;  // RNE
  return (unsigned short)r;
}
__device__ __forceinline__ float bf2f(unsigned short s) {
  return __uint_as_float(((unsigned int)s) << 16);
}

// ---------------------------------------------------------------------------
// K0: cast x -> bf16 (layout [B][M][D]) and normalize routing_leaves rows ->
// bf16 LHn (layout [L][T]).
// ---------------------------------------------------------------------------
__global__ __launch_bounds__(256) void k_prep(const float* __restrict__ x,
                                              const float* __restrict__ leaves,
                                              unsigned short* __restrict__ xb,
                                              unsigned short* __restrict__ lhn) {
  if (blockIdx.x < 2048) {
    size_t e = ((size_t)blockIdx.x * 256 + threadIdx.x) * 4;
    float4 v = *(const float4*)(x + e);
    ushort4 o;
    o.x = f2bf(v.x); o.y = f2bf(v.y); o.z = f2bf(v.z); o.w = f2bf(v.w);
    *(ushort4*)(xb + e) = o;
  } else {
    int l = threadIdx.x;
    if (l < L_) {
      const float* r = leaves + l * T_;
      float ss = 0.f;
      for (int i = 0; i < T_; ++i) ss = fmaf(r[i], r[i], ss);
      float inv = 1.0f / fmaxf(sqrtf(ss), 1e-12f);
      unsigned short* o = lhn + l * T_;
      for (int i = 0; i < T_; ++i) o[i] = f2bf(r[i] * inv);
    }
  }
}

// ---------------------------------------------------------------------------
// K1: exact entmax-1.5 over the D axis of route_weights [M,N,D,T].
// FOUR threads per (m,n,t) vector (32 elems each -> ~70 VGPRs, no spill risk,
// 8 waves/SIMD). 12 bisections bracket tau*, then one exact quadratic solve
// on the stabilized support (same fixed point as the reference sort).
// Output TRANSPOSED as Wq2[m][n][t][d] bf16 (contiguous GEMM B-fragments).
// ---------------------------------------------------------------------------
__global__ __launch_bounds__(256) void k_entmax(const float* __restrict__ rw,
                                                unsigned short* __restrict__ wq2) {
  const int tid = threadIdx.x;
  const int gv = blockIdx.x * 64 + (tid >> 2);  // vector id = (m*N+n)*T + t
  const int h = tid & 3;                        // quarter of D
  const int mn = gv >> 6;
  const int t = gv & 63;
  const float* base = rw + ((size_t)mn * D_ + h * 32) * T_ + t;
  float x[32];
#pragma unroll
  for (int i = 0; i < 32; ++i) x[i] = base[(size_t)i * T_];  // lanes = consecutive t
  float mx = x[0];
#pragma unroll
  for (int i = 1; i < 32; ++i) mx = fmaxf(mx, x[i]);
  mx = fmaxf(mx, __shfl_xor(mx, 1));
  mx = fmaxf(mx, __shfl_xor(mx, 2));
#pragma unroll
  for (int i = 0; i < 32; ++i) x[i] = (x[i] - mx) * 0.5f;  // x/2 - max(x/2)

  float lo = -1.0f, hi = 0.0f;
  for (int it = 0; it < 12; ++it) {
    float tau = 0.5f * (lo + hi);
    float f = 0.0f;
#pragma unroll
    for (int i = 0; i < 32; ++i) {
      float u = fmaxf(x[i] - tau, 0.0f);
      f = fmaf(u, u, f);
    }
    f += __shfl_xor(f, 1);
    f += __shfl_xor(f, 2);
    if (f >= 1.0f) lo = tau; else hi = tau;
  }
  float tau0 = 0.5f * (lo + hi);
  float cnt = 0.f, s1 = 0.f, s2 = 0.f;
#pragma unroll
  for (int i = 0; i < 32; ++i) {
    bool in = x[i] > tau0;
    float xv = in ? x[i] : 0.0f;
    cnt += in ? 1.0f : 0.0f;
    s1 += xv;
    s2 = fmaf(xv, xv, s2);
  }
  cnt += __shfl_xor(cnt, 1); cnt += __shfl_xor(cnt, 2);
  s1 += __shfl_xor(s1, 1);   s1 += __shfl_xor(s1, 2);
  s2 += __shfl_xor(s2, 1);   s2 += __shfl_xor(s2, 2);
  float mean = s1 / cnt;
  float ss = s2 - mean * s1;
  float delta = (1.0f - ss) / cnt;
  float tau = mean - sqrtf(fmaxf(delta, 0.0f));

  unsigned short pv[32];
#pragma unroll
  for (int i = 0; i < 32; ++i) {
    float u = fmaxf(x[i] - tau, 0.0f);
    pv[i] = f2bf(u * u);
  }
  uint4* o = (uint4*)(wq2 + (size_t)gv * D_ + h * 32);
#pragma unroll
  for (int j = 0; j < 4; ++j) {
    uint4 w;
    w.x = (unsigned)pv[8 * j + 0] | ((unsigned)pv[8 * j + 1] << 16);
    w.y = (unsigned)pv[8 * j + 2] | ((unsigned)pv[8 * j + 3] << 16);
    w.z = (unsigned)pv[8 * j + 4] | ((unsigned)pv[8 * j + 5] << 16);
    w.w = (unsigned)pv[8 * j + 6] | ((unsigned)pv[8 * j + 7] << 16);
    o[j] = w;
  }
}

// ---------------------------------------------------------------------------
// K2: priors = sum_d x[b,m,d] * W[m,n,d,t]  (per-m GEMM, K=128)
// Block = (n, b-tile of 128, m): 32 MFMA/wave (2 b-subtiles x 4 t x 4 k).
// Epilogue transposes through LDS -> contiguous dwordx4 stores to
// priors[n][m][b][t].
// ---------------------------------------------------------------------------
#define BS_STRIDE 136
__global__ __launch_bounds__(256) void k_priors(const unsigned short* __restrict__ xb,
                                                const unsigned short* __restrict__ wq2,
                                                unsigned short* __restrict__ priors) {
  const int n = blockIdx.x, bt = blockIdx.y, m = blockIdx.z;
  const int tid = threadIdx.x;
  const int wid = tid >> 6, lane = tid & 63;
  const int row16 = lane & 15, quad = lane >> 4;
  __shared__ __align__(16) unsigned short Bs[64 * BS_STRIDE];
  __shared__ __align__(16) unsigned short Ct[128 * 72];

  const unsigned short* bsrc = wq2 + ((size_t)(m * N_ + n) * T_) * D_;  // 64x128 contiguous
  {
    int tr = tid >> 4;
    int c = tid & 15;
#pragma unroll
    for (int p = 0; p < 4; ++p) {
      int row = p * 16 + tr;
      uint4 v = *(const uint4*)(bsrc + row * D_ + c * 8);
      *(uint4*)&Bs[row * BS_STRIDE + c * 8] = v;
    }
  }
  __syncthreads();

  short8 afr[2][4];
#pragma unroll
  for (int sub = 0; sub < 2; ++sub) {
    const int brow = bt * 128 + wid * 32 + sub * 16 + row16;
    const unsigned short* aptr = xb + ((size_t)brow * M_ + m) * D_ + quad * 8;
#pragma unroll
    for (int ks = 0; ks < 4; ++ks) afr[sub][ks] = *(const short8*)(aptr + ks * 32);
  }

  floatx4 acc[2][4];
#pragma unroll
  for (int sub = 0; sub < 2; ++sub)
#pragma unroll
    for (int cf = 0; cf < 4; ++cf) acc[sub][cf] = (floatx4){0.f, 0.f, 0.f, 0.f};

#pragma unroll
  for (int cf = 0; cf < 4; ++cf) {
#pragma unroll
    for (int ks = 0; ks < 4; ++ks) {
      short8 bfr = *(const short8*)&Bs[(cf * 16 + row16) * BS_STRIDE + ks * 32 + quad * 8];
#pragma unroll
      for (int sub = 0; sub < 2; ++sub)
        acc[sub][cf] = __builtin_amdgcn_mfma_f32_16x16x32_bf16(afr[sub][ks], bfr, acc[sub][cf], 0, 0, 0);
    }
  }

#pragma unroll
  for (int sub = 0; sub < 2; ++sub)
#pragma unroll
    for (int cf = 0; cf < 4; ++cf)
#pragma unroll
      for (int r = 0; r < 4; ++r)
        Ct[(wid * 32 + sub * 16 + quad * 4 + r) * 72 + cf * 16 + row16] = f2bf(acc[sub][cf][r]);
  __syncthreads();

#pragma unroll
  for (int it = 0; it < 2; ++it) {
    int row = it * 64 + (tid >> 2), seg = tid & 3;
    uint4 w0 = *(const uint4*)&Ct[row * 72 + seg * 16];
    uint4 w1 = *(const uint4*)&Ct[row * 72 + seg * 16 + 8];
    unsigned short* dst = priors + (((size_t)n * M_ + m) * B_ + bt * 128 + row) * T_ + seg * 16;
    *(uint4*)dst = w0;
    *(uint4*)(dst + 8) = w1;
  }
}

// ---------------------------------------------------------------------------
// K3: block = (n, 4 b's); WAVE w owns b = bt*4 + w end-to-end.
// Each wave: votes[64m x 128l] = sigmoid(P_b @ LHn^T) via 64 MFMA (C regs =
// 128 VGPR), then mean-over-m / dis / softmax / weighted-sum / LayerNorm all
// in-wave (registers + shfl_xor). ONE __syncthreads (P staging) total.
// ---------------------------------------------------------------------------
#define PSTRIDE 72
__global__ __launch_bounds__(256) void k_route(const unsigned short* __restrict__ priors,
                                               const unsigned short* __restrict__ lhn,
                                               const float* __restrict__ thr,
                                               const float* __restrict__ gamma,
                                               const float* __restrict__ beta,
                                               float* __restrict__ out) {
  const int n = blockIdx.x, bt = blockIdx.y;
  const int tid = threadIdx.x;
  const int wid = tid >> 6, lane = tid & 63;
  const int row16 = lane & 15, quad = lane >> 4;

  __shared__ __align__(16) unsigned short P4[4 * 64 * PSTRIDE];  // [b_local][m][t]
  __shared__ float probW[4][64];

  {  // stage P for 4 b's: coalesced 16B/lane, rows of priors[n][m][b][t]
    int mrow = tid >> 3, seg = tid & 7;
#pragma unroll
    for (int bl = 0; bl < 4; ++bl) {
#pragma unroll
      for (int it = 0; it < 2; ++it) {
        int mm = it * 32 + mrow;
        const unsigned short* src =
            priors + (((size_t)n * M_ + mm) * B_ + bt * 4 + bl) * T_ + seg * 8;
        *(uint4*)&P4[(bl * 64 + mm) * PSTRIDE + seg * 8] = *(const uint4*)src;
      }
    }
  }
  __syncthreads();

  const unsigned short* Pw = &P4[wid * 64 * PSTRIDE];
  short8 afr[4][2];  // A[m = mt*16+row16][k = ks*32+quad*8+j]
#pragma unroll
  for (int mt = 0; mt < 4; ++mt)
#pragma unroll
    for (int ks = 0; ks < 2; ++ks)
      afr[mt][ks] = *(const short8*)&Pw[(mt * 16 + row16) * PSTRIDE + ks * 32 + quad * 8];

  floatx4 acc[4][8];  // C[m = mt*16+quad*4+r][l = lt*16+row16]
#pragma unroll
  for (int mt = 0; mt < 4; ++mt)
#pragma unroll
    for (int lt = 0; lt < 8; ++lt) acc[mt][lt] = (floatx4){0.f, 0.f, 0.f, 0.f};

#pragma unroll
  for (int lt = 0; lt < 8; ++lt) {
#pragma unroll
    for (int ks = 0; ks < 2; ++ks) {
      short8 bfr = *(const short8*)(lhn + (lt * 16 + row16) * T_ + ks * 32 + quad * 8);
#pragma unroll
      for (int mt = 0; mt < 4; ++mt)
        acc[mt][lt] = __builtin_amdgcn_mfma_f32_16x16x32_bf16(afr[mt][ks], bfr, acc[mt][lt], 0, 0, 0);
    }
  }

  // sigmoid in place
#pragma unroll
  for (int mt = 0; mt < 4; ++mt)
#pragma unroll
    for (int lt = 0; lt < 8; ++lt)
#pragma unroll
      for (int r = 0; r < 4; ++r)
        acc[mt][lt][r] = 1.0f / (1.0f + __expf(-acc[mt][lt][r]));

  // mean over m (regs over mt,r + shfl over quad bits); all lanes get mc[lt]
  float mc[8];
#pragma unroll
  for (int lt = 0; lt < 8; ++lt) {
    float s = 0.f;
#pragma unroll
    for (int mt = 0; mt < 4; ++mt)
#pragma unroll
      for (int r = 0; r < 4; ++r) s += acc[mt][lt][r];
    s += __shfl_xor(s, 16);
    s += __shfl_xor(s, 32);
    mc[lt] = s * (1.0f / 64.0f);
  }

  // dis[m]: sum over l = regs (lt) + shfl over row16 bits (butterfly: all lanes)
  float dis[4][4];
#pragma unroll
  for (int mt = 0; mt < 4; ++mt)
#pragma unroll
    for (int r = 0; r < 4; ++r) {
      float s = 0.f;
#pragma unroll
      for (int lt = 0; lt < 8; ++lt) {
        float df = acc[mt][lt][r] - mc[lt];
        s = fmaf(df, df, s);
      }
      dis[mt][r] = s;
    }
#pragma unroll
  for (int off = 1; off <= 8; off <<= 1)
#pragma unroll
    for (int mt = 0; mt < 4; ++mt)
#pragma unroll
      for (int r = 0; r < 4; ++r) dis[mt][r] += __shfl_xor(dis[mt][r], off);

  // weight + softmax over m (m = mt*16 + quad*4 + r; reduce regs + quad bits)
  float w[4][4];
#pragma unroll
  for (int mt = 0; mt < 4; ++mt)
#pragma unroll
    for (int r = 0; r < 4; ++r) {
      float th = thr[(mt * 16 + quad * 4 + r) * N_ + n];
      w[mt][r] = fmaxf(th * th - dis[mt][r] * (1.0f / 128.0f), 0.0f);
    }
  float mxw = w[0][0];
#pragma unroll
  for (int mt = 0; mt < 4; ++mt)
#pragma unroll
    for (int r = 0; r < 4; ++r) mxw = fmaxf(mxw, w[mt][r]);
  mxw = fmaxf(mxw, __shfl_xor(mxw, 16));
  mxw = fmaxf(mxw, __shfl_xor(mxw, 32));
  float ssum = 0.f;
  float e[4][4];
#pragma unroll
  for (int mt = 0; mt < 4; ++mt)
#pragma unroll
    for (int r = 0; r < 4; ++r) {
      e[mt][r] = __expf(w[mt][r] - mxw);
      ssum += e[mt][r];
    }
  ssum += __shfl_xor(ssum, 16);
  ssum += __shfl_xor(ssum, 32);
  float inv = 1.0f / ssum;
  if (row16 == 0) {
#pragma unroll
    for (int mt = 0; mt < 4; ++mt)
#pragma unroll
      for (int r = 0; r < 4; ++r)
        probW[wid][mt * 16 + quad * 4 + r] = e[mt][r] * inv;
  }
  // same-wave LDS write->read: compiler inserts lgkmcnt wait (no barrier needed)

  // weighted sum over m, t = lane
  float o = 0.f;
#pragma unroll
  for (int mm = 0; mm < 64; ++mm)
    o = fmaf(probW[wid][mm], bf2f(Pw[mm * PSTRIDE + lane]), o);

  // LayerNorm over t (64 lanes)
  float mu = o;
#pragma unroll
  for (int off = 1; off <= 32; off <<= 1) mu += __shfl_xor(mu, off);
  mu *= (1.0f / 64.0f);
  float df = o - mu;
  float var = df * df;
#pragma unroll
  for (int off = 1; off <= 32; off <<= 1) var += __shfl_xor(var, off);
  var *= (1.0f / 64.0f);
  float res = df * rsqrtf(var + 1e-5f) * gamma[lane] + beta[lane];
  out[((size_t)(bt * 4 + wid) * N_ + n) * T_ + lane] = res;
}

// ---------------------------------------------------------------------------
// Workspace layout (bytes):
//   Wq2    [M][N][T][D] bf16 : off 0,           33,554,432
//   priors [N][M][B][T] bf16 : off 33,554,432,  67,108,864
//   xb     [B][M][D]    bf16 : off 100,663,296,  4,194,304
//   LHn    [L][T]       bf16 : off 104,857,600,     16,384
// ---------------------------------------------------------------------------
extern "C" void kernel_launch(void* const* d_in, const int* in_sizes, int n_in,
                              void* d_out, int out_size, void* d_ws, size_t ws_size,
                              hipStream_t stream) {
  const float* x = (const float*)d_in[0];
  const float* rw = (const float*)d_in[1];
  const float* thr = (const float*)d_in[2];
  const float* leaves = (const float*)d_in[3];
  const float* gamma = (const float*)d_in[4];
  const float* beta = (const float*)d_in[5];
  float* out = (float*)d_out;

  char* ws = (char*)d_ws;
  unsigned short* wq2 = (unsigned short*)(ws);
  unsigned short* priors = (unsigned short*)(ws + 33554432);
  unsigned short* xb = (unsigned short*)(ws + 33554432 + 67108864);
  unsigned short* lhn = (unsigned short*)(ws + 33554432 + 67108864 + 4194304);

  hipLaunchKernelGGL(k_prep, dim3(2049), dim3(256), 0, stream, x, leaves, xb, lhn);
  hipLaunchKernelGGL(k_entmax, dim3(2048), dim3(256), 0, stream, rw, wq2);
  hipLaunchKernelGGL(k_priors, dim3(32, 2, 64), dim3(256), 0, stream, xb, wq2, priors);
  hipLaunchKernelGGL(k_route, dim3(32, 64), dim3(256), 0, stream, priors, lhn, thr, gamma, beta, out);
}

// Round 5
// 228.093 us; speedup vs baseline: 1.0436x; 1.0436x over previous
//
#include <hip/hip_runtime.h>
#include <hip/hip_bf16.h>
#include <math.h>

// Problem sizes (fixed by reference): B=256, M=64, N=32, D=128, T=64, L=128
#define B_ 256
#define M_ 64
#define N_ 32
#define D_ 128
#define T_ 64
#define L_ 128

typedef __attribute__((ext_vector_type(8))) short short8;   // 8 bf16 = 4 VGPRs (MFMA A/B frag)
typedef __attribute__((ext_vector_type(4))) float floatx4;  // MFMA C/D frag

__device__ __forceinline__ unsigned short f2bf(float f) {
  unsigned int u = __float_as_uint(f);
  unsigned int r = (u + 0x7fffu + ((u >> 16) & 1u)) >> 16;  // RNE
  return (unsigned short)r;
}
__device__ __forceinline__ float bf2f(unsigned short s) {
  return __uint_as_float(((unsigned int)s) << 16);
}

// ---------------------------------------------------------------------------
// K0: cast x -> bf16 (layout [B][M][D]) and normalize routing_leaves rows ->
// bf16 LHn (layout [L][T]).
// ---------------------------------------------------------------------------
__global__ __launch_bounds__(256) void k_prep(const float* __restrict__ x,
                                              const float* __restrict__ leaves,
                                              unsigned short* __restrict__ xb,
                                              unsigned short* __restrict__ lhn) {
  if (blockIdx.x < 2048) {
    size_t e = ((size_t)blockIdx.x * 256 + threadIdx.x) * 4;
    float4 v = *(const float4*)(x + e);
    ushort4 o;
    o.x = f2bf(v.x); o.y = f2bf(v.y); o.z = f2bf(v.z); o.w = f2bf(v.w);
    *(ushort4*)(xb + e) = o;
  } else {
    int l = threadIdx.x;
    if (l < L_) {
      const float* r = leaves + l * T_;
      float ss = 0.f;
      for (int i = 0; i < T_; ++i) ss = fmaf(r[i], r[i], ss);
      float inv = 1.0f / fmaxf(sqrtf(ss), 1e-12f);
      unsigned short* o = lhn + l * T_;
      for (int i = 0; i < T_; ++i) o[i] = f2bf(r[i] * inv);
    }
  }
}

// ---------------------------------------------------------------------------
// K1: exact entmax-1.5 over the D axis of route_weights [M,N,D,T].
// FOUR threads per (m,n,t) vector (32 elems each). 12 bisections bracket
// tau*, then one exact quadratic solve on the stabilized support.
// Output TRANSPOSED as Wq2[m][n][t][d] bf16 (contiguous GEMM B-fragments).
// ---------------------------------------------------------------------------
__global__ __launch_bounds__(256) void k_entmax(const float* __restrict__ rw,
                                                unsigned short* __restrict__ wq2) {
  const int tid = threadIdx.x;
  const int gv = blockIdx.x * 64 + (tid >> 2);  // vector id = (m*N+n)*T + t
  const int h = tid & 3;                        // quarter of D
  const int mn = gv >> 6;
  const int t = gv & 63;
  const float* base = rw + ((size_t)mn * D_ + h * 32) * T_ + t;
  float x[32];
#pragma unroll
  for (int i = 0; i < 32; ++i) x[i] = base[(size_t)i * T_];  // lanes = consecutive t
  float mx = x[0];
#pragma unroll
  for (int i = 1; i < 32; ++i) mx = fmaxf(mx, x[i]);
  mx = fmaxf(mx, __shfl_xor(mx, 1));
  mx = fmaxf(mx, __shfl_xor(mx, 2));
#pragma unroll
  for (int i = 0; i < 32; ++i) x[i] = (x[i] - mx) * 0.5f;  // x/2 - max(x/2)

  float lo = -1.0f, hi = 0.0f;
  for (int it = 0; it < 12; ++it) {
    float tau = 0.5f * (lo + hi);
    float f = 0.0f;
#pragma unroll
    for (int i = 0; i < 32; ++i) {
      float u = fmaxf(x[i] - tau, 0.0f);
      f = fmaf(u, u, f);
    }
    f += __shfl_xor(f, 1);
    f += __shfl_xor(f, 2);
    if (f >= 1.0f) lo = tau; else hi = tau;
  }
  float tau0 = 0.5f * (lo + hi);
  float cnt = 0.f, s1 = 0.f, s2 = 0.f;
#pragma unroll
  for (int i = 0; i < 32; ++i) {
    bool in = x[i] > tau0;
    float xv = in ? x[i] : 0.0f;
    cnt += in ? 1.0f : 0.0f;
    s1 += xv;
    s2 = fmaf(xv, xv, s2);
  }
  cnt += __shfl_xor(cnt, 1); cnt += __shfl_xor(cnt, 2);
  s1 += __shfl_xor(s1, 1);   s1 += __shfl_xor(s1, 2);
  s2 += __shfl_xor(s2, 1);   s2 += __shfl_xor(s2, 2);
  float mean = s1 / cnt;
  float ss = s2 - mean * s1;
  float delta = (1.0f - ss) / cnt;
  float tau = mean - sqrtf(fmaxf(delta, 0.0f));

  unsigned short pv[32];
#pragma unroll
  for (int i = 0; i < 32; ++i) {
    float u = fmaxf(x[i] - tau, 0.0f);
    pv[i] = f2bf(u * u);
  }
  uint4* o = (uint4*)(wq2 + (size_t)gv * D_ + h * 32);
#pragma unroll
  for (int j = 0; j < 4; ++j) {
    uint4 w;
    w.x = (unsigned)pv[8 * j + 0] | ((unsigned)pv[8 * j + 1] << 16);
    w.y = (unsigned)pv[8 * j + 2] | ((unsigned)pv[8 * j + 3] << 16);
    w.z = (unsigned)pv[8 * j + 4] | ((unsigned)pv[8 * j + 5] << 16);
    w.w = (unsigned)pv[8 * j + 6] | ((unsigned)pv[8 * j + 7] << 16);
    o[j] = w;
  }
}

// ---------------------------------------------------------------------------
// K2: priors = sum_d x[b,m,d] * W[m,n,d,t]  (per-m GEMM, K=128)
// Block = (n, b-tile of 128, m): 32 MFMA/wave. Epilogue transposes through
// LDS -> contiguous dwordx4 stores to priors[n][m][b][t].
// ---------------------------------------------------------------------------
#define BS_STRIDE 136
__global__ __launch_bounds__(256) void k_priors(const unsigned short* __restrict__ xb,
                                                const unsigned short* __restrict__ wq2,
                                                unsigned short* __restrict__ priors) {
  const int n = blockIdx.x, bt = blockIdx.y, m = blockIdx.z;
  const int tid = threadIdx.x;
  const int wid = tid >> 6, lane = tid & 63;
  const int row16 = lane & 15, quad = lane >> 4;
  __shared__ __align__(16) unsigned short Bs[64 * BS_STRIDE];
  __shared__ __align__(16) unsigned short Ct[128 * 72];

  const unsigned short* bsrc = wq2 + ((size_t)(m * N_ + n) * T_) * D_;  // 64x128 contiguous
  {
    int tr = tid >> 4;
    int c = tid & 15;
#pragma unroll
    for (int p = 0; p < 4; ++p) {
      int row = p * 16 + tr;
      uint4 v = *(const uint4*)(bsrc + row * D_ + c * 8);
      *(uint4*)&Bs[row * BS_STRIDE + c * 8] = v;
    }
  }
  __syncthreads();

  short8 afr[2][4];
#pragma unroll
  for (int sub = 0; sub < 2; ++sub) {
    const int brow = bt * 128 + wid * 32 + sub * 16 + row16;
    const unsigned short* aptr = xb + ((size_t)brow * M_ + m) * D_ + quad * 8;
#pragma unroll
    for (int ks = 0; ks < 4; ++ks) afr[sub][ks] = *(const short8*)(aptr + ks * 32);
  }

  floatx4 acc[2][4];
#pragma unroll
  for (int sub = 0; sub < 2; ++sub)
#pragma unroll
    for (int cf = 0; cf < 4; ++cf) acc[sub][cf] = (floatx4){0.f, 0.f, 0.f, 0.f};

#pragma unroll
  for (int cf = 0; cf < 4; ++cf) {
#pragma unroll
    for (int ks = 0; ks < 4; ++ks) {
      short8 bfr = *(const short8*)&Bs[(cf * 16 + row16) * BS_STRIDE + ks * 32 + quad * 8];
#pragma unroll
      for (int sub = 0; sub < 2; ++sub)
        acc[sub][cf] = __builtin_amdgcn_mfma_f32_16x16x32_bf16(afr[sub][ks], bfr, acc[sub][cf], 0, 0, 0);
    }
  }

#pragma unroll
  for (int sub = 0; sub < 2; ++sub)
#pragma unroll
    for (int cf = 0; cf < 4; ++cf)
#pragma unroll
      for (int r = 0; r < 4; ++r)
        Ct[(wid * 32 + sub * 16 + quad * 4 + r) * 72 + cf * 16 + row16] = f2bf(acc[sub][cf][r]);
  __syncthreads();

#pragma unroll
  for (int it = 0; it < 2; ++it) {
    int row = it * 64 + (tid >> 2), seg = tid & 3;
    uint4 w0 = *(const uint4*)&Ct[row * 72 + seg * 16];
    uint4 w1 = *(const uint4*)&Ct[row * 72 + seg * 16 + 8];
    unsigned short* dst = priors + (((size_t)n * M_ + m) * B_ + bt * 128 + row) * T_ + seg * 16;
    *(uint4*)dst = w0;
    *(uint4*)(dst + 8) = w1;
  }
}

// ---------------------------------------------------------------------------
// K3: one block per (b,n), 4 waves, votes in 32 AGPR/thread (R3 shape —
// small register footprint, ~5-6 waves/SIMD). R5 changes: barriers 6 -> 4;
// no idle-wave phases except the final LN; mc combine folded into each lane
// (broadcast reads of mcp are conflict-free); softmax computed redundantly
// per-wave from disA, probW written/read same-wave (no barrier).
// ---------------------------------------------------------------------------
__global__ __launch_bounds__(256) void k_route(const unsigned short* __restrict__ priors,
                                               const unsigned short* __restrict__ lhn,
                                               const float* __restrict__ thr,
                                               const float* __restrict__ gamma,
                                               const float* __restrict__ beta,
                                               float* __restrict__ out) {
  const int n = blockIdx.x, b = blockIdx.y;
  const int tid = threadIdx.x;
  const int wid = tid >> 6, lane = tid & 63;
  const int row16 = lane & 15, quad = lane >> 4;

  __shared__ __align__(16) unsigned short Ps[64 * 72];  // P [m][t] bf16 (64 data + 8 pad)
  __shared__ float mcp[4 * 128];   // per-wave column partial sums
  __shared__ float disA[64];
  __shared__ float probW[4][64];   // per-wave full softmax vector
  __shared__ float part[4 * 64];

  float th_l = thr[lane * N_ + n];  // hoisted: m = lane (used in phase D)

  {  // stage P rows: priors[n][m][b][t], m-rows at stride B*T
    int mm = tid >> 2, c = tid & 3;
    const unsigned short* src = priors + (((size_t)n * M_ + mm) * B_ + b) * T_ + c * 16;
    uint4 v0 = *(const uint4*)(src);
    uint4 v1 = *(const uint4*)(src + 8);
    *(uint4*)&Ps[mm * 72 + c * 16] = v0;
    *(uint4*)&Ps[mm * 72 + c * 16 + 8] = v1;
  }
  __syncthreads();  // B1

  short8 afr[2];
#pragma unroll
  for (int ks = 0; ks < 2; ++ks)
    afr[ks] = *(const short8*)&Ps[(wid * 16 + row16) * 72 + ks * 32 + quad * 8];

  floatx4 acc[8];
#pragma unroll
  for (int cf = 0; cf < 8; ++cf) acc[cf] = (floatx4){0.f, 0.f, 0.f, 0.f};

#pragma unroll
  for (int cf = 0; cf < 8; ++cf) {
#pragma unroll
    for (int ks = 0; ks < 2; ++ks) {
      short8 bfr = *(const short8*)(lhn + (cf * 16 + row16) * T_ + ks * 32 + quad * 8);
      acc[cf] = __builtin_amdgcn_mfma_f32_16x16x32_bf16(afr[ks], bfr, acc[cf], 0, 0, 0);
    }
  }

  // sigmoid: v[cf][r] for m = wid*16+quad*4+r, l = cf*16+row16
  float v[8][4];
#pragma unroll
  for (int cf = 0; cf < 8; ++cf)
#pragma unroll
    for (int r = 0; r < 4; ++r) v[cf][r] = 1.0f / (1.0f + __expf(-acc[cf][r]));

  // per-wave column sums over this wave's 16 m's -> mcp[wid][l]
#pragma unroll
  for (int cf = 0; cf < 8; ++cf) {
    float s = v[cf][0] + v[cf][1] + v[cf][2] + v[cf][3];
    s += __shfl_xor(s, 16);
    s += __shfl_xor(s, 32);
    if (quad == 0) mcp[wid * 128 + cf * 16 + row16] = s;
  }
  __syncthreads();  // B2

  // each lane folds the 4 wave-partials itself (broadcast reads, no conflict)
  float mcv[8];
#pragma unroll
  for (int cf = 0; cf < 8; ++cf) {
    int l = cf * 16 + row16;
    mcv[cf] = (mcp[l] + mcp[128 + l] + mcp[256 + l] + mcp[384 + l]) * (1.0f / 64.0f);
  }

  // dis[m] = mean_l (v - mc)^2 : regs over cf + shfl butterfly over row16 bits
  float d[4];
#pragma unroll
  for (int r = 0; r < 4; ++r) {
    float s = 0.f;
#pragma unroll
    for (int cf = 0; cf < 8; ++cf) {
      float df = v[cf][r] - mcv[cf];
      s = fmaf(df, df, s);
    }
    d[r] = s;
  }
#pragma unroll
  for (int off = 1; off <= 8; off <<= 1)
#pragma unroll
    for (int r = 0; r < 4; ++r) d[r] += __shfl_xor(d[r], off);
  if (row16 == 0) {
#pragma unroll
    for (int r = 0; r < 4; ++r) disA[wid * 16 + quad * 4 + r] = d[r] * (1.0f / 128.0f);
  }
  __syncthreads();  // B3

  // softmax over m, computed redundantly by EVERY wave (lane = m)
  {
    float dis = disA[lane];
    float w = fmaxf(th_l * th_l - dis, 0.0f);
    float mxw = w;
#pragma unroll
    for (int off = 1; off <= 32; off <<= 1) mxw = fmaxf(mxw, __shfl_xor(mxw, off));
    float e = __expf(w - mxw);
    float s = e;
#pragma unroll
    for (int off = 1; off <= 32; off <<= 1) s += __shfl_xor(s, off);
    probW[wid][lane] = e / s;  // same-wave write->read below; lgkmcnt handles it
  }

  // weighted-sum partials: wave wid handles m in [wid*16, wid*16+16), t = lane
  {
    float s = 0.f;
#pragma unroll
    for (int j = 0; j < 16; ++j) {
      int mm = wid * 16 + j;
      s = fmaf(probW[wid][mm], bf2f(Ps[mm * 72 + lane]), s);
    }
    part[wid * 64 + lane] = s;
  }
  __syncthreads();  // B4

  if (wid == 0) {  // final sum + LayerNorm over T (t = lane)
    float s = part[lane] + part[64 + lane] + part[128 + lane] + part[192 + lane];
    float mu = s;
#pragma unroll
    for (int off = 1; off <= 32; off <<= 1) mu += __shfl_xor(mu, off);
    mu *= (1.0f / 64.0f);
    float df = s - mu;
    float var = df * df;
#pragma unroll
    for (int off = 1; off <= 32; off <<= 1) var += __shfl_xor(var, off);
    var *= (1.0f / 64.0f);
    float o = df * rsqrtf(var + 1e-5f) * gamma[lane] + beta[lane];
    out[((size_t)b * N_ + n) * T_ + lane] = o;
  }
}

// ---------------------------------------------------------------------------
// Workspace layout (bytes):
//   Wq2    [M][N][T][D] bf16 : off 0,           33,554,432
//   priors [N][M][B][T] bf16 : off 33,554,432,  67,108,864
//   xb     [B][M][D]    bf16 : off 100,663,296,  4,194,304
//   LHn    [L][T]       bf16 : off 104,857,600,     16,384
// ---------------------------------------------------------------------------
extern "C" void kernel_launch(void* const* d_in, const int* in_sizes, int n_in,
                              void* d_out, int out_size, void* d_ws, size_t ws_size,
                              hipStream_t stream) {
  const float* x = (const float*)d_in[0];
  const float* rw = (const float*)d_in[1];
  const float* thr = (const float*)d_in[2];
  const float* leaves = (const float*)d_in[3];
  const float* gamma = (const float*)d_in[4];
  const float* beta = (const float*)d_in[5];
  float* out = (float*)d_out;

  char* ws = (char*)d_ws;
  unsigned short* wq2 = (unsigned short*)(ws);
  unsigned short* priors = (unsigned short*)(ws + 33554432);
  unsigned short* xb = (unsigned short*)(ws + 33554432 + 67108864);
  unsigned short* lhn = (unsigned short*)(ws + 33554432 + 67108864 + 4194304);

  hipLaunchKernelGGL(k_prep, dim3(2049), dim3(256), 0, stream, x, leaves, xb, lhn);
  hipLaunchKernelGGL(k_entmax, dim3(2048), dim3(256), 0, stream, rw, wq2);
  hipLaunchKernelGGL(k_priors, dim3(32, 2, 64), dim3(256), 0, stream, xb, wq2, priors);
  hipLaunchKernelGGL(k_route, dim3(32, 256), dim3(256), 0, stream, priors, lhn, thr, gamma, beta, out);
}

// Round 6
// 213.587 us; speedup vs baseline: 1.1145x; 1.0679x over previous
//
#include <hip/hip_runtime.h>
#include <hip/hip_bf16.h>
#include <math.h>

// Problem sizes (fixed by reference): B=256, M=64, N=32, D=128, T=64, L=128
#define B_ 256
#define M_ 64
#define N_ 32
#define D_ 128
#define T_ 64
#define L_ 128

typedef __attribute__((ext_vector_type(8))) short short8;   // 8 bf16 = 4 VGPRs (MFMA A/B frag)
typedef __attribute__((ext_vector_type(4))) float floatx4;  // MFMA C/D frag

__device__ __forceinline__ unsigned short f2bf(float f) {
  unsigned int u = __float_as_uint(f);
  unsigned int r = (u + 0x7fffu + ((u >> 16) & 1u)) >> 16;  // RNE
  return (unsigned short)r;
}
__device__ __forceinline__ float bf2f(unsigned short s) {
  return __uint_as_float(((unsigned int)s) << 16);
}

// ---------------------------------------------------------------------------
// K1: exact entmax-1.5 over D of route_weights [M,N,D,T] (blocks < 2048),
// PLUS folded prep work (blocks >= 2048): cast x->bf16, normalize leaves.
// entmax: 4 threads/vector, 12 bisections + exact solve on support.
// Output TRANSPOSED as Wq2[m][n][t][d] bf16.
// ---------------------------------------------------------------------------
__global__ __launch_bounds__(256) void k_entmax(const float* __restrict__ rw,
                                                unsigned short* __restrict__ wq2,
                                                const float* __restrict__ x,
                                                const float* __restrict__ leaves,
                                                unsigned short* __restrict__ xb,
                                                unsigned short* __restrict__ lhn) {
  const int tid = threadIdx.x;
  if (blockIdx.x >= 2048) {  // prep path
    int bid = blockIdx.x - 2048;
    if (bid < 2048) {
      size_t e = ((size_t)bid * 256 + tid) * 4;
      float4 v = *(const float4*)(x + e);
      ushort4 o;
      o.x = f2bf(v.x); o.y = f2bf(v.y); o.z = f2bf(v.z); o.w = f2bf(v.w);
      *(ushort4*)(xb + e) = o;
    } else if (tid < L_) {
      const float* r = leaves + tid * T_;
      float ss = 0.f;
      for (int i = 0; i < T_; ++i) ss = fmaf(r[i], r[i], ss);
      float inv = 1.0f / fmaxf(sqrtf(ss), 1e-12f);
      unsigned short* o = lhn + tid * T_;
      for (int i = 0; i < T_; ++i) o[i] = f2bf(r[i] * inv);
    }
    return;
  }

  const int gv = blockIdx.x * 64 + (tid >> 2);  // vector id = (m*N+n)*T + t
  const int h = tid & 3;                        // quarter of D
  const int mn = gv >> 6;
  const int t = gv & 63;
  const float* base = rw + ((size_t)mn * D_ + h * 32) * T_ + t;
  float xv_[32];
#pragma unroll
  for (int i = 0; i < 32; ++i) xv_[i] = base[(size_t)i * T_];
  float mx = xv_[0];
#pragma unroll
  for (int i = 1; i < 32; ++i) mx = fmaxf(mx, xv_[i]);
  mx = fmaxf(mx, __shfl_xor(mx, 1));
  mx = fmaxf(mx, __shfl_xor(mx, 2));
#pragma unroll
  for (int i = 0; i < 32; ++i) xv_[i] = (xv_[i] - mx) * 0.5f;

  float lo = -1.0f, hi = 0.0f;
  for (int it = 0; it < 12; ++it) {
    float tau = 0.5f * (lo + hi);
    float f = 0.0f;
#pragma unroll
    for (int i = 0; i < 32; ++i) {
      float u = fmaxf(xv_[i] - tau, 0.0f);
      f = fmaf(u, u, f);
    }
    f += __shfl_xor(f, 1);
    f += __shfl_xor(f, 2);
    if (f >= 1.0f) lo = tau; else hi = tau;
  }
  float tau0 = 0.5f * (lo + hi);
  float cnt = 0.f, s1 = 0.f, s2 = 0.f;
#pragma unroll
  for (int i = 0; i < 32; ++i) {
    bool in = xv_[i] > tau0;
    float q = in ? xv_[i] : 0.0f;
    cnt += in ? 1.0f : 0.0f;
    s1 += q;
    s2 = fmaf(q, q, s2);
  }
  cnt += __shfl_xor(cnt, 1); cnt += __shfl_xor(cnt, 2);
  s1 += __shfl_xor(s1, 1);   s1 += __shfl_xor(s1, 2);
  s2 += __shfl_xor(s2, 1);   s2 += __shfl_xor(s2, 2);
  float mean = s1 / cnt;
  float ss = s2 - mean * s1;
  float delta = (1.0f - ss) / cnt;
  float tau = mean - sqrtf(fmaxf(delta, 0.0f));

  unsigned short pv[32];
#pragma unroll
  for (int i = 0; i < 32; ++i) {
    float u = fmaxf(xv_[i] - tau, 0.0f);
    pv[i] = f2bf(u * u);
  }
  uint4* o = (uint4*)(wq2 + (size_t)gv * D_ + h * 32);
#pragma unroll
  for (int j = 0; j < 4; ++j) {
    uint4 w;
    w.x = (unsigned)pv[8 * j + 0] | ((unsigned)pv[8 * j + 1] << 16);
    w.y = (unsigned)pv[8 * j + 2] | ((unsigned)pv[8 * j + 3] << 16);
    w.z = (unsigned)pv[8 * j + 4] | ((unsigned)pv[8 * j + 5] << 16);
    w.w = (unsigned)pv[8 * j + 6] | ((unsigned)pv[8 * j + 7] << 16);
    o[j] = w;
  }
}

// ---------------------------------------------------------------------------
// K2: priors GEMM. Block = (n, bt of 128 b's, m); 32 MFMA/wave.
// Epilogue transposes through LDS then stores to priors[n][g][m][bq][t]
// (g = b>>3, bq = b&7): 1KB-contiguous bursts, and k_route's whole block
// input becomes one contiguous 64KB slab.
// ---------------------------------------------------------------------------
#define BS_STRIDE 136
__global__ __launch_bounds__(256) void k_priors(const unsigned short* __restrict__ xb,
                                                const unsigned short* __restrict__ wq2,
                                                unsigned short* __restrict__ priors) {
  const int n = blockIdx.x, bt = blockIdx.y, m = blockIdx.z;
  const int tid = threadIdx.x;
  const int wid = tid >> 6, lane = tid & 63;
  const int row16 = lane & 15, quad = lane >> 4;
  __shared__ __align__(16) unsigned short Bs[64 * BS_STRIDE];
  __shared__ __align__(16) unsigned short Ct[128 * 72];

  const unsigned short* bsrc = wq2 + ((size_t)(m * N_ + n) * T_) * D_;  // 64x128 contiguous
  {
    int tr = tid >> 4;
    int c = tid & 15;
#pragma unroll
    for (int p = 0; p < 4; ++p) {
      int row = p * 16 + tr;
      uint4 v = *(const uint4*)(bsrc + row * D_ + c * 8);
      *(uint4*)&Bs[row * BS_STRIDE + c * 8] = v;
    }
  }
  __syncthreads();

  short8 afr[2][4];
#pragma unroll
  for (int sub = 0; sub < 2; ++sub) {
    const int brow = bt * 128 + wid * 32 + sub * 16 + row16;
    const unsigned short* aptr = xb + ((size_t)brow * M_ + m) * D_ + quad * 8;
#pragma unroll
    for (int ks = 0; ks < 4; ++ks) afr[sub][ks] = *(const short8*)(aptr + ks * 32);
  }

  floatx4 acc[2][4];
#pragma unroll
  for (int sub = 0; sub < 2; ++sub)
#pragma unroll
    for (int cf = 0; cf < 4; ++cf) acc[sub][cf] = (floatx4){0.f, 0.f, 0.f, 0.f};

#pragma unroll
  for (int cf = 0; cf < 4; ++cf) {
#pragma unroll
    for (int ks = 0; ks < 4; ++ks) {
      short8 bfr = *(const short8*)&Bs[(cf * 16 + row16) * BS_STRIDE + ks * 32 + quad * 8];
#pragma unroll
      for (int sub = 0; sub < 2; ++sub)
        acc[sub][cf] = __builtin_amdgcn_mfma_f32_16x16x32_bf16(afr[sub][ks], bfr, acc[sub][cf], 0, 0, 0);
    }
  }

#pragma unroll
  for (int sub = 0; sub < 2; ++sub)
#pragma unroll
    for (int cf = 0; cf < 4; ++cf)
#pragma unroll
      for (int r = 0; r < 4; ++r)
        Ct[(wid * 32 + sub * 16 + quad * 4 + r) * 72 + cf * 16 + row16] = f2bf(acc[sub][cf][r]);
  __syncthreads();

  {  // store: thread tid -> 64B; 16 lanes -> one 1KB contiguous chunk
    int q = tid >> 4, s = tid & 15;
    int row = q * 8 + (s >> 1);   // b-local 0..127
    int half = s & 1;
    const unsigned short* src = &Ct[row * 72 + half * 32];
    unsigned short* dst = priors +
        ((((size_t)n * 32 + bt * 16 + q) * M_ + m) * 8 + (s >> 1)) * T_ + half * 32;
    uint4 a0 = *(const uint4*)(src);
    uint4 a1 = *(const uint4*)(src + 8);
    uint4 a2 = *(const uint4*)(src + 16);
    uint4 a3 = *(const uint4*)(src + 24);
    *(uint4*)(dst) = a0;
    *(uint4*)(dst + 8) = a1;
    *(uint4*)(dst + 16) = a2;
    *(uint4*)(dst + 24) = a3;
  }
}

// ---------------------------------------------------------------------------
// K3: block = (n, g) over 8 b's; 4 waves x 2 b's, wave owns b end-to-end.
// Stage = ONE contiguous 64KB read. Votes computed in two l-slices of 64
// (acc = 64 VGPR, reused), running dis accumulation; mean/dis/softmax all
// in-wave via shfl (R4-verified math). P kept in LDS (pad stride 520 ->
// 2-way conflicts only). ONE barrier total.
// ---------------------------------------------------------------------------
#define PROW 520  // shorts per m-row: 8*64 data + 8 pad
__global__ __launch_bounds__(256) void k_route(const unsigned short* __restrict__ priors,
                                               const unsigned short* __restrict__ lhn,
                                               const float* __restrict__ thr,
                                               const float* __restrict__ gamma,
                                               const float* __restrict__ beta,
                                               float* __restrict__ out) {
  const int n = blockIdx.x, g = blockIdx.y;
  const int tid = threadIdx.x;
  const int wid = tid >> 6, lane = tid & 63;
  const int col = lane & 15, quad = lane >> 4;

  __shared__ __align__(16) unsigned short Pb[64 * PROW];  // [m][bq][t] + pad
  __shared__ float thL[64];
  __shared__ float probL[8][64];

  {  // 64KB contiguous stage
    const unsigned short* src = priors + ((size_t)n * 32 + g) * (M_ * 8 * T_);
#pragma unroll
    for (int i = 0; i < 16; ++i) {
      int e = (i * 256 + tid) * 8;  // element offset
      int m = e >> 9, rem = e & 511;
      *(uint4*)&Pb[m * PROW + rem] = *(const uint4*)(src + e);
    }
  }
  if (tid < 64) thL[tid] = thr[tid * N_ + n];
  __syncthreads();  // the only barrier

  const float lg = gamma[lane], lb = beta[lane];

#pragma unroll
  for (int bl = 0; bl < 2; ++bl) {
    const int b_local = wid * 2 + bl;

    short8 afr[4][2];  // A[m = mt*16+col][k = ks*32+quad*8+j]
#pragma unroll
    for (int mt = 0; mt < 4; ++mt)
#pragma unroll
      for (int ks = 0; ks < 2; ++ks)
        afr[mt][ks] = *(const short8*)&Pb[(mt * 16 + col) * PROW + b_local * T_ + ks * 32 + quad * 8];

    float dis[4][4];
#pragma unroll
    for (int mt = 0; mt < 4; ++mt)
#pragma unroll
      for (int r = 0; r < 4; ++r) dis[mt][r] = 0.f;

#pragma unroll
    for (int ls = 0; ls < 2; ++ls) {
      floatx4 acc[4][4];  // C[m = mt*16+quad*4+r][l = ls*64+lt*16+col]
#pragma unroll
      for (int mt = 0; mt < 4; ++mt)
#pragma unroll
        for (int lt = 0; lt < 4; ++lt) acc[mt][lt] = (floatx4){0.f, 0.f, 0.f, 0.f};

#pragma unroll
      for (int lt = 0; lt < 4; ++lt) {
#pragma unroll
        for (int ks = 0; ks < 2; ++ks) {
          short8 bfr = *(const short8*)(lhn + (ls * 64 + lt * 16 + col) * T_ + ks * 32 + quad * 8);
#pragma unroll
          for (int mt = 0; mt < 4; ++mt)
            acc[mt][lt] = __builtin_amdgcn_mfma_f32_16x16x32_bf16(afr[mt][ks], bfr, acc[mt][lt], 0, 0, 0);
        }
      }

      // sigmoid in place
#pragma unroll
      for (int mt = 0; mt < 4; ++mt)
#pragma unroll
        for (int lt = 0; lt < 4; ++lt)
#pragma unroll
          for (int r = 0; r < 4; ++r)
            acc[mt][lt][r] = 1.0f / (1.0f + __expf(-acc[mt][lt][r]));

      // mc[lt] = mean over m (regs over mt,r + shfl over quad bits)
      float mc[4];
#pragma unroll
      for (int lt = 0; lt < 4; ++lt) {
        float s = 0.f;
#pragma unroll
        for (int mt = 0; mt < 4; ++mt)
#pragma unroll
          for (int r = 0; r < 4; ++r) s += acc[mt][lt][r];
        s += __shfl_xor(s, 16);
        s += __shfl_xor(s, 32);
        mc[lt] = s * (1.0f / 64.0f);
      }

      // dis partial over this l-slice
#pragma unroll
      for (int mt = 0; mt < 4; ++mt)
#pragma unroll
        for (int r = 0; r < 4; ++r) {
          float s = 0.f;
#pragma unroll
          for (int lt = 0; lt < 4; ++lt) {
            float df = acc[mt][lt][r] - mc[lt];
            s = fmaf(df, df, s);
          }
          dis[mt][r] += s;
        }
    }

    // butterfly over col bits -> dis[m] summed over all 128 l
#pragma unroll
    for (int off = 1; off <= 8; off <<= 1)
#pragma unroll
      for (int mt = 0; mt < 4; ++mt)
#pragma unroll
        for (int r = 0; r < 4; ++r) dis[mt][r] += __shfl_xor(dis[mt][r], off);

    // weight + softmax over m (m = mt*16 + quad*4 + r)
    float w[4][4];
#pragma unroll
    for (int mt = 0; mt < 4; ++mt)
#pragma unroll
      for (int r = 0; r < 4; ++r) {
        float th = thL[mt * 16 + quad * 4 + r];
        w[mt][r] = fmaxf(th * th - dis[mt][r] * (1.0f / 128.0f), 0.0f);
      }
    float mxw = w[0][0];
#pragma unroll
    for (int mt = 0; mt < 4; ++mt)
#pragma unroll
      for (int r = 0; r < 4; ++r) mxw = fmaxf(mxw, w[mt][r]);
    mxw = fmaxf(mxw, __shfl_xor(mxw, 16));
    mxw = fmaxf(mxw, __shfl_xor(mxw, 32));
    float e[4][4], ssum = 0.f;
#pragma unroll
    for (int mt = 0; mt < 4; ++mt)
#pragma unroll
      for (int r = 0; r < 4; ++r) {
        e[mt][r] = __expf(w[mt][r] - mxw);
        ssum += e[mt][r];
      }
    ssum += __shfl_xor(ssum, 16);
    ssum += __shfl_xor(ssum, 32);
    float inv = 1.0f / ssum;
    if (col == 0) {
#pragma unroll
      for (int mt = 0; mt < 4; ++mt)
#pragma unroll
        for (int r = 0; r < 4; ++r)
          probL[b_local][mt * 16 + quad * 4 + r] = e[mt][r] * inv;
    }
    // same-wave LDS write->read: compiler inserts lgkmcnt wait

    // weighted sum over m, t = lane
    float o = 0.f;
#pragma unroll
    for (int mm = 0; mm < 64; ++mm)
      o = fmaf(probL[b_local][mm], bf2f(Pb[mm * PROW + b_local * T_ + lane]), o);

    // LayerNorm over t
    float mu = o;
#pragma unroll
    for (int off = 1; off <= 32; off <<= 1) mu += __shfl_xor(mu, off);
    mu *= (1.0f / 64.0f);
    float df = o - mu;
    float var = df * df;
#pragma unroll
    for (int off = 1; off <= 32; off <<= 1) var += __shfl_xor(var, off);
    var *= (1.0f / 64.0f);
    float res = df * rsqrtf(var + 1e-5f) * lg + lb;
    out[((size_t)(g * 8 + b_local) * N_ + n) * T_ + lane] = res;
  }
}

// ---------------------------------------------------------------------------
// Workspace layout (bytes):
//   Wq2    [M][N][T][D]     bf16 : off 0,           33,554,432
//   priors [N][G32][M][8][T] bf16: off 33,554,432,  67,108,864
//   xb     [B][M][D]        bf16 : off 100,663,296,  4,194,304
//   LHn    [L][T]           bf16 : off 104,857,600,     16,384
// ---------------------------------------------------------------------------
extern "C" void kernel_launch(void* const* d_in, const int* in_sizes, int n_in,
                              void* d_out, int out_size, void* d_ws, size_t ws_size,
                              hipStream_t stream) {
  const float* x = (const float*)d_in[0];
  const float* rw = (const float*)d_in[1];
  const float* thr = (const float*)d_in[2];
  const float* leaves = (const float*)d_in[3];
  const float* gamma = (const float*)d_in[4];
  const float* beta = (const float*)d_in[5];
  float* out = (float*)d_out;

  char* ws = (char*)d_ws;
  unsigned short* wq2 = (unsigned short*)(ws);
  unsigned short* priors = (unsigned short*)(ws + 33554432);
  unsigned short* xb = (unsigned short*)(ws + 33554432 + 67108864);
  unsigned short* lhn = (unsigned short*)(ws + 33554432 + 67108864 + 4194304);

  hipLaunchKernelGGL(k_entmax, dim3(4097), dim3(256), 0, stream, rw, wq2, x, leaves, xb, lhn);
  hipLaunchKernelGGL(k_priors, dim3(32, 2, 64), dim3(256), 0, stream, xb, wq2, priors);
  hipLaunchKernelGGL(k_route, dim3(32, 32), dim3(256), 0, stream, priors, lhn, thr, gamma, beta, out);
}

// Round 7
// 209.234 us; speedup vs baseline: 1.1377x; 1.0208x over previous
//
#include <hip/hip_runtime.h>
#include <hip/hip_bf16.h>
#include <math.h>

// Problem sizes (fixed by reference): B=256, M=64, N=32, D=128, T=64, L=128
#define B_ 256
#define M_ 64
#define N_ 32
#define D_ 128
#define T_ 64
#define L_ 128

typedef __attribute__((ext_vector_type(8))) short short8;   // 8 bf16 = 4 VGPRs (MFMA A/B frag)
typedef __attribute__((ext_vector_type(4))) float floatx4;  // MFMA C/D frag

__device__ __forceinline__ unsigned short f2bf(float f) {
  unsigned int u = __float_as_uint(f);
  unsigned int r = (u + 0x7fffu + ((u >> 16) & 1u)) >> 16;  // RNE
  return (unsigned short)r;
}
__device__ __forceinline__ float bf2f(unsigned short s) {
  return __uint_as_float(((unsigned int)s) << 16);
}

// ---------------------------------------------------------------------------
// K1: exact entmax-1.5 over D of route_weights [M,N,D,T] (blocks < 2048),
// PLUS folded prep work (blocks >= 2048): cast x->bf16, normalize leaves.
// entmax: 4 threads/vector, 12 bisections + exact solve on support.
// Output TRANSPOSED as Wq2[m][n][t][d] bf16.
// ---------------------------------------------------------------------------
__global__ __launch_bounds__(256) void k_entmax(const float* __restrict__ rw,
                                                unsigned short* __restrict__ wq2,
                                                const float* __restrict__ x,
                                                const float* __restrict__ leaves,
                                                unsigned short* __restrict__ xb,
                                                unsigned short* __restrict__ lhn) {
  const int tid = threadIdx.x;
  if (blockIdx.x >= 2048) {  // prep path
    int bid = blockIdx.x - 2048;
    if (bid < 2048) {
      size_t e = ((size_t)bid * 256 + tid) * 4;
      float4 v = *(const float4*)(x + e);
      ushort4 o;
      o.x = f2bf(v.x); o.y = f2bf(v.y); o.z = f2bf(v.z); o.w = f2bf(v.w);
      *(ushort4*)(xb + e) = o;
    } else if (tid < L_) {
      const float* r = leaves + tid * T_;
      float ss = 0.f;
      for (int i = 0; i < T_; ++i) ss = fmaf(r[i], r[i], ss);
      float inv = 1.0f / fmaxf(sqrtf(ss), 1e-12f);
      unsigned short* o = lhn + tid * T_;
      for (int i = 0; i < T_; ++i) o[i] = f2bf(r[i] * inv);
    }
    return;
  }

  const int gv = blockIdx.x * 64 + (tid >> 2);  // vector id = (m*N+n)*T + t
  const int h = tid & 3;                        // quarter of D
  const int mn = gv >> 6;
  const int t = gv & 63;
  const float* base = rw + ((size_t)mn * D_ + h * 32) * T_ + t;
  float xv_[32];
#pragma unroll
  for (int i = 0; i < 32; ++i) xv_[i] = base[(size_t)i * T_];
  float mx = xv_[0];
#pragma unroll
  for (int i = 1; i < 32; ++i) mx = fmaxf(mx, xv_[i]);
  mx = fmaxf(mx, __shfl_xor(mx, 1));
  mx = fmaxf(mx, __shfl_xor(mx, 2));
#pragma unroll
  for (int i = 0; i < 32; ++i) xv_[i] = (xv_[i] - mx) * 0.5f;

  float lo = -1.0f, hi = 0.0f;
  for (int it = 0; it < 12; ++it) {
    float tau = 0.5f * (lo + hi);
    float f = 0.0f;
#pragma unroll
    for (int i = 0; i < 32; ++i) {
      float u = fmaxf(xv_[i] - tau, 0.0f);
      f = fmaf(u, u, f);
    }
    f += __shfl_xor(f, 1);
    f += __shfl_xor(f, 2);
    if (f >= 1.0f) lo = tau; else hi = tau;
  }
  float tau0 = 0.5f * (lo + hi);
  float cnt = 0.f, s1 = 0.f, s2 = 0.f;
#pragma unroll
  for (int i = 0; i < 32; ++i) {
    bool in = xv_[i] > tau0;
    float q = in ? xv_[i] : 0.0f;
    cnt += in ? 1.0f : 0.0f;
    s1 += q;
    s2 = fmaf(q, q, s2);
  }
  cnt += __shfl_xor(cnt, 1); cnt += __shfl_xor(cnt, 2);
  s1 += __shfl_xor(s1, 1);   s1 += __shfl_xor(s1, 2);
  s2 += __shfl_xor(s2, 1);   s2 += __shfl_xor(s2, 2);
  float mean = s1 / cnt;
  float ss = s2 - mean * s1;
  float delta = (1.0f - ss) / cnt;
  float tau = mean - sqrtf(fmaxf(delta, 0.0f));

  unsigned short pv[32];
#pragma unroll
  for (int i = 0; i < 32; ++i) {
    float u = fmaxf(xv_[i] - tau, 0.0f);
    pv[i] = f2bf(u * u);
  }
  uint4* o = (uint4*)(wq2 + (size_t)gv * D_ + h * 32);
#pragma unroll
  for (int j = 0; j < 4; ++j) {
    uint4 w;
    w.x = (unsigned)pv[8 * j + 0] | ((unsigned)pv[8 * j + 1] << 16);
    w.y = (unsigned)pv[8 * j + 2] | ((unsigned)pv[8 * j + 3] << 16);
    w.z = (unsigned)pv[8 * j + 4] | ((unsigned)pv[8 * j + 5] << 16);
    w.w = (unsigned)pv[8 * j + 6] | ((unsigned)pv[8 * j + 7] << 16);
    o[j] = w;
  }
}

// ---------------------------------------------------------------------------
// K2: priors GEMM. ONE block per (m,n) covering ALL 256 b (2048 blocks).
// B-tile staged once; b in 2 chunks of 128 (keeps afr+acc at 64 VGPR so
// launch_bounds(256,4) holds -> 4 blocks/CU with ~35KB LDS).
// 64 MFMA/wave. Store layout priors[n][g8][m][bq][t].
// ---------------------------------------------------------------------------
#define BS_STRIDE 136
__global__ __launch_bounds__(256, 4) void k_priors(const unsigned short* __restrict__ xb,
                                                   const unsigned short* __restrict__ wq2,
                                                   unsigned short* __restrict__ priors) {
  const int m = blockIdx.x, n = blockIdx.y;
  const int tid = threadIdx.x;
  const int wid = tid >> 6, lane = tid & 63;
  const int row16 = lane & 15, quad = lane >> 4;
  __shared__ __align__(16) unsigned short Bs[64 * BS_STRIDE];
  __shared__ __align__(16) unsigned short Ct[128 * 72];

  const unsigned short* bsrc = wq2 + ((size_t)(m * N_ + n) * T_) * D_;  // 64x128 contiguous
  {
    int tr = tid >> 4;
    int c = tid & 15;
#pragma unroll
    for (int p = 0; p < 4; ++p) {
      int row = p * 16 + tr;
      uint4 v = *(const uint4*)(bsrc + row * D_ + c * 8);
      *(uint4*)&Bs[row * BS_STRIDE + c * 8] = v;
    }
  }
  __syncthreads();

#pragma unroll
  for (int c = 0; c < 2; ++c) {  // chunk of 128 b
    short8 afr[2][4];
#pragma unroll
    for (int sc = 0; sc < 2; ++sc) {
      const int brow = c * 128 + wid * 32 + sc * 16 + row16;
      const unsigned short* aptr = xb + ((size_t)brow * M_ + m) * D_ + quad * 8;
#pragma unroll
      for (int ks = 0; ks < 4; ++ks) afr[sc][ks] = *(const short8*)(aptr + ks * 32);
    }

    floatx4 acc[2][4];
#pragma unroll
    for (int sc = 0; sc < 2; ++sc)
#pragma unroll
      for (int cf = 0; cf < 4; ++cf) acc[sc][cf] = (floatx4){0.f, 0.f, 0.f, 0.f};

#pragma unroll
    for (int cf = 0; cf < 4; ++cf) {
#pragma unroll
      for (int ks = 0; ks < 4; ++ks) {
        short8 bfr = *(const short8*)&Bs[(cf * 16 + row16) * BS_STRIDE + ks * 32 + quad * 8];
#pragma unroll
        for (int sc = 0; sc < 2; ++sc)
          acc[sc][cf] = __builtin_amdgcn_mfma_f32_16x16x32_bf16(afr[sc][ks], bfr, acc[sc][cf], 0, 0, 0);
      }
    }

    if (c) __syncthreads();  // chunk-0 stores must finish before Ct reuse
#pragma unroll
    for (int sc = 0; sc < 2; ++sc)
#pragma unroll
      for (int cf = 0; cf < 4; ++cf)
#pragma unroll
        for (int r = 0; r < 4; ++r)
          Ct[(wid * 32 + sc * 16 + quad * 4 + r) * 72 + cf * 16 + row16] = f2bf(acc[sc][cf][r]);
    __syncthreads();

    {  // store 128 rows x 128B; 16 lanes = one 1KB contiguous chunk
      int q = tid >> 4, s = tid & 15;
      int row = q * 8 + (s >> 1);
      int half = s & 1;
      const unsigned short* src = &Ct[row * 72 + half * 32];
      unsigned short* dst = priors +
          ((((size_t)n * 32 + c * 16 + q) * M_ + m) * 8 + (s >> 1)) * T_ + half * 32;
      uint4 a0 = *(const uint4*)(src);
      uint4 a1 = *(const uint4*)(src + 8);
      uint4 a2 = *(const uint4*)(src + 16);
      uint4 a3 = *(const uint4*)(src + 24);
      *(uint4*)(dst) = a0;
      *(uint4*)(dst + 8) = a1;
      *(uint4*)(dst + 16) = a2;
      *(uint4*)(dst + 24) = a3;
    }
  }
}

// ---------------------------------------------------------------------------
// K3: block = (n, g4) over 4 b's; 4 waves, wave owns ONE b end-to-end.
// Stage = contiguous 512B-chunk reads (32KB total). LDS ~35KB -> 4 blocks/CU
// -> 16 waves/CU (~50% occ). Votes in two l-slices of 64 (acc 64 VGPR),
// in-wave mean/dis/softmax via shfl. ONE barrier.
// ---------------------------------------------------------------------------
#define PROW 264  // shorts per m-row: 4*64 data + 8 pad
__global__ __launch_bounds__(256, 4) void k_route(const unsigned short* __restrict__ priors,
                                                  const unsigned short* __restrict__ lhn,
                                                  const float* __restrict__ thr,
                                                  const float* __restrict__ gamma,
                                                  const float* __restrict__ beta,
                                                  float* __restrict__ out) {
  const int n = blockIdx.x, g4 = blockIdx.y;
  const int tid = threadIdx.x;
  const int wid = tid >> 6, lane = tid & 63;
  const int col = lane & 15, quad = lane >> 4;

  __shared__ __align__(16) unsigned short Pb[64 * PROW];  // [m][bq4][t] + pad
  __shared__ float thL[64];
  __shared__ float probL[4][64];

  {  // stage 32KB: per m, one contiguous 512B chunk of the g8 slab
    const unsigned short* src = priors + ((size_t)n * 32 + (g4 >> 1)) * (M_ * 8 * T_) + (g4 & 1) * 256;
#pragma unroll
    for (int i = 0; i < 8; ++i) {
      int idx = i * 256 + tid;        // uint4 slot 0..2047
      int m = idx >> 5, slot = idx & 31;
      *(uint4*)&Pb[m * PROW + slot * 8] = *(const uint4*)(src + (size_t)m * 512 + slot * 8);
    }
  }
  if (tid < 64) thL[tid] = thr[tid * N_ + n];
  __syncthreads();  // the only barrier

  const float lg = gamma[lane], lb = beta[lane];
  const int b_local = wid;

  short8 afr[4][2];  // A[m = mt*16+col][k = ks*32+quad*8+j]
#pragma unroll
  for (int mt = 0; mt < 4; ++mt)
#pragma unroll
    for (int ks = 0; ks < 2; ++ks)
      afr[mt][ks] = *(const short8*)&Pb[(mt * 16 + col) * PROW + b_local * T_ + ks * 32 + quad * 8];

  float dis[4][4];
#pragma unroll
  for (int mt = 0; mt < 4; ++mt)
#pragma unroll
    for (int r = 0; r < 4; ++r) dis[mt][r] = 0.f;

#pragma unroll
  for (int ls = 0; ls < 2; ++ls) {
    floatx4 acc[4][4];  // C[m = mt*16+quad*4+r][l = ls*64+lt*16+col]
#pragma unroll
    for (int mt = 0; mt < 4; ++mt)
#pragma unroll
      for (int lt = 0; lt < 4; ++lt) acc[mt][lt] = (floatx4){0.f, 0.f, 0.f, 0.f};

#pragma unroll
    for (int lt = 0; lt < 4; ++lt) {
#pragma unroll
      for (int ks = 0; ks < 2; ++ks) {
        short8 bfr = *(const short8*)(lhn + (ls * 64 + lt * 16 + col) * T_ + ks * 32 + quad * 8);
#pragma unroll
        for (int mt = 0; mt < 4; ++mt)
          acc[mt][lt] = __builtin_amdgcn_mfma_f32_16x16x32_bf16(afr[mt][ks], bfr, acc[mt][lt], 0, 0, 0);
      }
    }

    // sigmoid in place
#pragma unroll
    for (int mt = 0; mt < 4; ++mt)
#pragma unroll
      for (int lt = 0; lt < 4; ++lt)
#pragma unroll
        for (int r = 0; r < 4; ++r)
          acc[mt][lt][r] = 1.0f / (1.0f + __expf(-acc[mt][lt][r]));

    // mc[lt] = mean over m (regs over mt,r + shfl over quad bits)
    float mc[4];
#pragma unroll
    for (int lt = 0; lt < 4; ++lt) {
      float s = 0.f;
#pragma unroll
      for (int mt = 0; mt < 4; ++mt)
#pragma unroll
        for (int r = 0; r < 4; ++r) s += acc[mt][lt][r];
      s += __shfl_xor(s, 16);
      s += __shfl_xor(s, 32);
      mc[lt] = s * (1.0f / 64.0f);
    }

    // dis partial over this l-slice
#pragma unroll
    for (int mt = 0; mt < 4; ++mt)
#pragma unroll
      for (int r = 0; r < 4; ++r) {
        float s = 0.f;
#pragma unroll
        for (int lt = 0; lt < 4; ++lt) {
          float df = acc[mt][lt][r] - mc[lt];
          s = fmaf(df, df, s);
        }
        dis[mt][r] += s;
      }
  }

  // butterfly over col bits -> dis[m] summed over all 128 l
#pragma unroll
  for (int off = 1; off <= 8; off <<= 1)
#pragma unroll
    for (int mt = 0; mt < 4; ++mt)
#pragma unroll
      for (int r = 0; r < 4; ++r) dis[mt][r] += __shfl_xor(dis[mt][r], off);

  // weight + softmax over m (m = mt*16 + quad*4 + r)
  float w[4][4];
#pragma unroll
  for (int mt = 0; mt < 4; ++mt)
#pragma unroll
    for (int r = 0; r < 4; ++r) {
      float th = thL[mt * 16 + quad * 4 + r];
      w[mt][r] = fmaxf(th * th - dis[mt][r] * (1.0f / 128.0f), 0.0f);
    }
  float mxw = w[0][0];
#pragma unroll
  for (int mt = 0; mt < 4; ++mt)
#pragma unroll
    for (int r = 0; r < 4; ++r) mxw = fmaxf(mxw, w[mt][r]);
  mxw = fmaxf(mxw, __shfl_xor(mxw, 16));
  mxw = fmaxf(mxw, __shfl_xor(mxw, 32));
  float e[4][4], ssum = 0.f;
#pragma unroll
  for (int mt = 0; mt < 4; ++mt)
#pragma unroll
    for (int r = 0; r < 4; ++r) {
      e[mt][r] = __expf(w[mt][r] - mxw);
      ssum += e[mt][r];
    }
  ssum += __shfl_xor(ssum, 16);
  ssum += __shfl_xor(ssum, 32);
  float inv = 1.0f / ssum;
  if (col == 0) {
#pragma unroll
    for (int mt = 0; mt < 4; ++mt)
#pragma unroll
      for (int r = 0; r < 4; ++r)
        probL[b_local][mt * 16 + quad * 4 + r] = e[mt][r] * inv;
  }
  // same-wave LDS write->read: compiler inserts lgkmcnt wait

  // weighted sum over m, t = lane
  float o = 0.f;
#pragma unroll
  for (int mm = 0; mm < 64; ++mm)
    o = fmaf(probL[b_local][mm], bf2f(Pb[mm * PROW + b_local * T_ + lane]), o);

  // LayerNorm over t
  float mu = o;
#pragma unroll
  for (int off = 1; off <= 32; off <<= 1) mu += __shfl_xor(mu, off);
  mu *= (1.0f / 64.0f);
  float df = o - mu;
  float var = df * df;
#pragma unroll
  for (int off = 1; off <= 32; off <<= 1) var += __shfl_xor(var, off);
  var *= (1.0f / 64.0f);
  float res = df * rsqrtf(var + 1e-5f) * lg + lb;
  out[((size_t)(g4 * 4 + b_local) * N_ + n) * T_ + lane] = res;
}

// ---------------------------------------------------------------------------
// Workspace layout (bytes):
//   Wq2    [M][N][T][D]      bf16 : off 0,           33,554,432
//   priors [N][G32][M][8][T] bf16 : off 33,554,432,  67,108,864
//   xb     [B][M][D]         bf16 : off 100,663,296,  4,194,304
//   LHn    [L][T]            bf16 : off 104,857,600,     16,384
// ---------------------------------------------------------------------------
extern "C" void kernel_launch(void* const* d_in, const int* in_sizes, int n_in,
                              void* d_out, int out_size, void* d_ws, size_t ws_size,
                              hipStream_t stream) {
  const float* x = (const float*)d_in[0];
  const float* rw = (const float*)d_in[1];
  const float* thr = (const float*)d_in[2];
  const float* leaves = (const float*)d_in[3];
  const float* gamma = (const float*)d_in[4];
  const float* beta = (const float*)d_in[5];
  float* out = (float*)d_out;

  char* ws = (char*)d_ws;
  unsigned short* wq2 = (unsigned short*)(ws);
  unsigned short* priors = (unsigned short*)(ws + 33554432);
  unsigned short* xb = (unsigned short*)(ws + 33554432 + 67108864);
  unsigned short* lhn = (unsigned short*)(ws + 33554432 + 67108864 + 4194304);

  hipLaunchKernelGGL(k_entmax, dim3(4097), dim3(256), 0, stream, rw, wq2, x, leaves, xb, lhn);
  hipLaunchKernelGGL(k_priors, dim3(64, 32), dim3(256), 0, stream, xb, wq2, priors);
  hipLaunchKernelGGL(k_route, dim3(32, 64), dim3(256), 0, stream, priors, lhn, thr, gamma, beta, out);
}

// Round 8
// 202.970 us; speedup vs baseline: 1.1728x; 1.0309x over previous
//
#include <hip/hip_runtime.h>
#include <hip/hip_bf16.h>
#include <math.h>

// Problem sizes (fixed by reference): B=256, M=64, N=32, D=128, T=64, L=128
#define B_ 256
#define M_ 64
#define N_ 32
#define D_ 128
#define T_ 64
#define L_ 128

typedef __attribute__((ext_vector_type(8))) short short8;   // 8 bf16 = 4 VGPRs (MFMA A/B frag)
typedef __attribute__((ext_vector_type(4))) float floatx4;  // MFMA C/D frag

__device__ __forceinline__ unsigned short f2bf(float f) {
  unsigned int u = __float_as_uint(f);
  unsigned int r = (u + 0x7fffu + ((u >> 16) & 1u)) >> 16;  // RNE
  return (unsigned short)r;
}
__device__ __forceinline__ float bf2f(unsigned short s) {
  return __uint_as_float(((unsigned int)s) << 16);
}

// ---------------------------------------------------------------------------
// K1: exact entmax-1.5 over D of route_weights [M,N,D,T] (blocks < 2048),
// PLUS folded prep (blocks >= 2048): x -> bf16 TRANSPOSED to xb2[M][B][D]
// (gives k_priors a contiguous A-slab), normalize leaves -> LHn bf16.
// entmax: 4 threads/vector, 12 bisections + exact solve on support.
// ---------------------------------------------------------------------------
__global__ __launch_bounds__(256) void k_entmax(const float* __restrict__ rw,
                                                unsigned short* __restrict__ wq2,
                                                const float* __restrict__ x,
                                                const float* __restrict__ leaves,
                                                unsigned short* __restrict__ xb2,
                                                unsigned short* __restrict__ lhn) {
  const int tid = threadIdx.x;
  if (blockIdx.x >= 2048) {  // prep path
    int bid = blockIdx.x - 2048;
    if (bid < 2048) {
      size_t e = ((size_t)bid * 256 + tid) * 4;
      int b = (int)(e >> 13);        // / (M*D = 8192)
      int rem = (int)(e & 8191);
      int mm = rem >> 7, dd = rem & 127;
      float4 v = *(const float4*)(x + e);
      ushort4 o;
      o.x = f2bf(v.x); o.y = f2bf(v.y); o.z = f2bf(v.z); o.w = f2bf(v.w);
      *(ushort4*)(xb2 + ((size_t)mm * B_ + b) * D_ + dd) = o;
    } else if (tid < L_) {
      const float* r = leaves + tid * T_;
      float ss = 0.f;
      for (int i = 0; i < T_; ++i) ss = fmaf(r[i], r[i], ss);
      float inv = 1.0f / fmaxf(sqrtf(ss), 1e-12f);
      unsigned short* o = lhn + tid * T_;
      for (int i = 0; i < T_; ++i) o[i] = f2bf(r[i] * inv);
    }
    return;
  }

  const int gv = blockIdx.x * 64 + (tid >> 2);  // vector id = (m*N+n)*T + t
  const int h = tid & 3;                        // quarter of D
  const int mn = gv >> 6;
  const int t = gv & 63;
  const float* base = rw + ((size_t)mn * D_ + h * 32) * T_ + t;
  float xv_[32];
#pragma unroll
  for (int i = 0; i < 32; ++i) xv_[i] = base[(size_t)i * T_];
  float mx = xv_[0];
#pragma unroll
  for (int i = 1; i < 32; ++i) mx = fmaxf(mx, xv_[i]);
  mx = fmaxf(mx, __shfl_xor(mx, 1));
  mx = fmaxf(mx, __shfl_xor(mx, 2));
#pragma unroll
  for (int i = 0; i < 32; ++i) xv_[i] = (xv_[i] - mx) * 0.5f;

  float lo = -1.0f, hi = 0.0f;
  for (int it = 0; it < 12; ++it) {
    float tau = 0.5f * (lo + hi);
    float f = 0.0f;
#pragma unroll
    for (int i = 0; i < 32; ++i) {
      float u = fmaxf(xv_[i] - tau, 0.0f);
      f = fmaf(u, u, f);
    }
    f += __shfl_xor(f, 1);
    f += __shfl_xor(f, 2);
    if (f >= 1.0f) lo = tau; else hi = tau;
  }
  float tau0 = 0.5f * (lo + hi);
  float cnt = 0.f, s1 = 0.f, s2 = 0.f;
#pragma unroll
  for (int i = 0; i < 32; ++i) {
    bool in = xv_[i] > tau0;
    float q = in ? xv_[i] : 0.0f;
    cnt += in ? 1.0f : 0.0f;
    s1 += q;
    s2 = fmaf(q, q, s2);
  }
  cnt += __shfl_xor(cnt, 1); cnt += __shfl_xor(cnt, 2);
  s1 += __shfl_xor(s1, 1);   s1 += __shfl_xor(s1, 2);
  s2 += __shfl_xor(s2, 1);   s2 += __shfl_xor(s2, 2);
  float mean = s1 / cnt;
  float ss = s2 - mean * s1;
  float delta = (1.0f - ss) / cnt;
  float tau = mean - sqrtf(fmaxf(delta, 0.0f));

  unsigned short pv[32];
#pragma unroll
  for (int i = 0; i < 32; ++i) {
    float u = fmaxf(xv_[i] - tau, 0.0f);
    pv[i] = f2bf(u * u);
  }
  uint4* o = (uint4*)(wq2 + (size_t)gv * D_ + h * 32);
#pragma unroll
  for (int j = 0; j < 4; ++j) {
    uint4 w;
    w.x = (unsigned)pv[8 * j + 0] | ((unsigned)pv[8 * j + 1] << 16);
    w.y = (unsigned)pv[8 * j + 2] | ((unsigned)pv[8 * j + 3] << 16);
    w.z = (unsigned)pv[8 * j + 4] | ((unsigned)pv[8 * j + 5] << 16);
    w.w = (unsigned)pv[8 * j + 6] | ((unsigned)pv[8 * j + 7] << 16);
    o[j] = w;
  }
}

// ---------------------------------------------------------------------------
// K2: priors GEMM. ONE block per (m,n), all 256 b in 2 chunks of 128.
// R8: A-chunk staged as ONE contiguous 32KB slab from xb2[M][B][D] into LDS
// (was: 16B gathers at 16KB stride). A-tile LDS unioned with Ct transpose
// buffer (afr consumed into regs before overwrite). LDS 52KB -> 3 blocks/CU.
// Store layout priors[n][g8][m][bq][t].
// ---------------------------------------------------------------------------
#define BS_STRIDE 136
__global__ __launch_bounds__(256, 3) void k_priors(const unsigned short* __restrict__ xb2,
                                                   const unsigned short* __restrict__ wq2,
                                                   unsigned short* __restrict__ priors) {
  const int m = blockIdx.x, n = blockIdx.y;
  const int tid = threadIdx.x;
  const int wid = tid >> 6, lane = tid & 63;
  const int row16 = lane & 15, quad = lane >> 4;
  __shared__ __align__(16) unsigned short Bs[64 * BS_STRIDE];
  __shared__ __align__(16) unsigned short AsCt[128 * BS_STRIDE];  // As (A-tile) / Ct (transpose) union

  const unsigned short* bsrc = wq2 + ((size_t)(m * N_ + n) * T_) * D_;  // 64x128 contiguous
  {
    int tr = tid >> 4;
    int c = tid & 15;
#pragma unroll
    for (int p = 0; p < 4; ++p) {
      int row = p * 16 + tr;
      uint4 v = *(const uint4*)(bsrc + row * D_ + c * 8);
      *(uint4*)&Bs[row * BS_STRIDE + c * 8] = v;
    }
  }
  __syncthreads();

#pragma unroll
  for (int c = 0; c < 2; ++c) {  // chunk of 128 b
    {  // stage A-chunk: contiguous 32KB from xb2[m][c*128 ...][:]
      const unsigned short* asrc = xb2 + ((size_t)m * B_ + c * 128) * D_;
#pragma unroll
      for (int i = 0; i < 8; ++i) {
        int idx = i * 256 + tid;        // uint4 slot 0..2047
        int brow = idx >> 4;            // 16 uint4 per 128-short row
        int off = (idx & 15) * 8;
        *(uint4*)&AsCt[brow * BS_STRIDE + off] = *(const uint4*)(asrc + (size_t)idx * 8);
      }
    }
    __syncthreads();

    short8 afr[2][4];
#pragma unroll
    for (int sc = 0; sc < 2; ++sc) {
      const int brow = wid * 32 + sc * 16 + row16;
#pragma unroll
      for (int ks = 0; ks < 4; ++ks)
        afr[sc][ks] = *(const short8*)&AsCt[brow * BS_STRIDE + ks * 32 + quad * 8];
    }
    __syncthreads();  // all afr reads done before Ct overwrites As

    floatx4 acc[2][4];
#pragma unroll
    for (int sc = 0; sc < 2; ++sc)
#pragma unroll
      for (int cf = 0; cf < 4; ++cf) acc[sc][cf] = (floatx4){0.f, 0.f, 0.f, 0.f};

#pragma unroll
    for (int cf = 0; cf < 4; ++cf) {
#pragma unroll
      for (int ks = 0; ks < 4; ++ks) {
        short8 bfr = *(const short8*)&Bs[(cf * 16 + row16) * BS_STRIDE + ks * 32 + quad * 8];
#pragma unroll
        for (int sc = 0; sc < 2; ++sc)
          acc[sc][cf] = __builtin_amdgcn_mfma_f32_16x16x32_bf16(afr[sc][ks], bfr, acc[sc][cf], 0, 0, 0);
      }
    }

#pragma unroll
    for (int sc = 0; sc < 2; ++sc)
#pragma unroll
      for (int cf = 0; cf < 4; ++cf)
#pragma unroll
        for (int r = 0; r < 4; ++r)
          AsCt[(wid * 32 + sc * 16 + quad * 4 + r) * 72 + cf * 16 + row16] = f2bf(acc[sc][cf][r]);
    __syncthreads();

    {  // store 128 rows x 128B; 16 lanes = one 1KB contiguous chunk
      int q = tid >> 4, s = tid & 15;
      int row = q * 8 + (s >> 1);
      int half = s & 1;
      const unsigned short* src = &AsCt[row * 72 + half * 32];
      unsigned short* dst = priors +
          ((((size_t)n * 32 + c * 16 + q) * M_ + m) * 8 + (s >> 1)) * T_ + half * 32;
      uint4 a0 = *(const uint4*)(src);
      uint4 a1 = *(const uint4*)(src + 8);
      uint4 a2 = *(const uint4*)(src + 16);
      uint4 a3 = *(const uint4*)(src + 24);
      *(uint4*)(dst) = a0;
      *(uint4*)(dst + 8) = a1;
      *(uint4*)(dst + 16) = a2;
      *(uint4*)(dst + 24) = a3;
    }
    if (c == 0) __syncthreads();  // stores read Ct; next chunk re-stages As
  }
}

// ---------------------------------------------------------------------------
// K3: block = (n, g4) over 4 b's; wave owns ONE b end-to-end. Stage =
// contiguous 512B-chunk reads. Votes in two l-slices (acc 64 VGPR), in-wave
// mean/dis/softmax via shfl. R8: weighted sum vectorized (ushort4, 4 t/lane,
// m partitioned by quad) + float4 coalesced output store. ONE barrier.
// ---------------------------------------------------------------------------
#define PROW 264  // shorts per m-row: 4*64 data + 8 pad
__global__ __launch_bounds__(256, 4) void k_route(const unsigned short* __restrict__ priors,
                                                  const unsigned short* __restrict__ lhn,
                                                  const float* __restrict__ thr,
                                                  const float* __restrict__ gamma,
                                                  const float* __restrict__ beta,
                                                  float* __restrict__ out) {
  const int n = blockIdx.x, g4 = blockIdx.y;
  const int tid = threadIdx.x;
  const int wid = tid >> 6, lane = tid & 63;
  const int col = lane & 15, quad = lane >> 4;

  __shared__ __align__(16) unsigned short Pb[64 * PROW];  // [m][bq4][t] + pad
  __shared__ float thL[64];
  __shared__ float probL[4][64];

  {  // stage 32KB: per m, one contiguous 512B chunk of the g8 slab
    const unsigned short* src = priors + ((size_t)n * 32 + (g4 >> 1)) * (M_ * 8 * T_) + (g4 & 1) * 256;
#pragma unroll
    for (int i = 0; i < 8; ++i) {
      int idx = i * 256 + tid;        // uint4 slot 0..2047
      int m = idx >> 5, slot = idx & 31;
      *(uint4*)&Pb[m * PROW + slot * 8] = *(const uint4*)(src + (size_t)m * 512 + slot * 8);
    }
  }
  if (tid < 64) thL[tid] = thr[tid * N_ + n];
  __syncthreads();  // the only barrier

  const int b_local = wid;

  short8 afr[4][2];  // A[m = mt*16+col][k = ks*32+quad*8+j]
#pragma unroll
  for (int mt = 0; mt < 4; ++mt)
#pragma unroll
    for (int ks = 0; ks < 2; ++ks)
      afr[mt][ks] = *(const short8*)&Pb[(mt * 16 + col) * PROW + b_local * T_ + ks * 32 + quad * 8];

  float dis[4][4];
#pragma unroll
  for (int mt = 0; mt < 4; ++mt)
#pragma unroll
    for (int r = 0; r < 4; ++r) dis[mt][r] = 0.f;

#pragma unroll
  for (int ls = 0; ls < 2; ++ls) {
    floatx4 acc[4][4];  // C[m = mt*16+quad*4+r][l = ls*64+lt*16+col]
#pragma unroll
    for (int mt = 0; mt < 4; ++mt)
#pragma unroll
      for (int lt = 0; lt < 4; ++lt) acc[mt][lt] = (floatx4){0.f, 0.f, 0.f, 0.f};

#pragma unroll
    for (int lt = 0; lt < 4; ++lt) {
#pragma unroll
      for (int ks = 0; ks < 2; ++ks) {
        short8 bfr = *(const short8*)(lhn + (ls * 64 + lt * 16 + col) * T_ + ks * 32 + quad * 8);
#pragma unroll
        for (int mt = 0; mt < 4; ++mt)
          acc[mt][lt] = __builtin_amdgcn_mfma_f32_16x16x32_bf16(afr[mt][ks], bfr, acc[mt][lt], 0, 0, 0);
      }
    }

#pragma unroll
    for (int mt = 0; mt < 4; ++mt)
#pragma unroll
      for (int lt = 0; lt < 4; ++lt)
#pragma unroll
        for (int r = 0; r < 4; ++r)
          acc[mt][lt][r] = 1.0f / (1.0f + __expf(-acc[mt][lt][r]));

    float mc[4];
#pragma unroll
    for (int lt = 0; lt < 4; ++lt) {
      float s = 0.f;
#pragma unroll
      for (int mt = 0; mt < 4; ++mt)
#pragma unroll
        for (int r = 0; r < 4; ++r) s += acc[mt][lt][r];
      s += __shfl_xor(s, 16);
      s += __shfl_xor(s, 32);
      mc[lt] = s * (1.0f / 64.0f);
    }

#pragma unroll
    for (int mt = 0; mt < 4; ++mt)
#pragma unroll
      for (int r = 0; r < 4; ++r) {
        float s = 0.f;
#pragma unroll
        for (int lt = 0; lt < 4; ++lt) {
          float df = acc[mt][lt][r] - mc[lt];
          s = fmaf(df, df, s);
        }
        dis[mt][r] += s;
      }
  }

#pragma unroll
  for (int off = 1; off <= 8; off <<= 1)
#pragma unroll
    for (int mt = 0; mt < 4; ++mt)
#pragma unroll
      for (int r = 0; r < 4; ++r) dis[mt][r] += __shfl_xor(dis[mt][r], off);

  float w[4][4];
#pragma unroll
  for (int mt = 0; mt < 4; ++mt)
#pragma unroll
    for (int r = 0; r < 4; ++r) {
      float th = thL[mt * 16 + quad * 4 + r];
      w[mt][r] = fmaxf(th * th - dis[mt][r] * (1.0f / 128.0f), 0.0f);
    }
  float mxw = w[0][0];
#pragma unroll
  for (int mt = 0; mt < 4; ++mt)
#pragma unroll
    for (int r = 0; r < 4; ++r) mxw = fmaxf(mxw, w[mt][r]);
  mxw = fmaxf(mxw, __shfl_xor(mxw, 16));
  mxw = fmaxf(mxw, __shfl_xor(mxw, 32));
  float e[4][4], ssum = 0.f;
#pragma unroll
  for (int mt = 0; mt < 4; ++mt)
#pragma unroll
    for (int r = 0; r < 4; ++r) {
      e[mt][r] = __expf(w[mt][r] - mxw);
      ssum += e[mt][r];
    }
  ssum += __shfl_xor(ssum, 16);
  ssum += __shfl_xor(ssum, 32);
  float inv = 1.0f / ssum;
  if (col == 0) {
#pragma unroll
    for (int mt = 0; mt < 4; ++mt)
#pragma unroll
      for (int r = 0; r < 4; ++r)
        probL[b_local][mt * 16 + quad * 4 + r] = e[mt][r] * inv;
  }
  // same-wave LDS write->read: compiler inserts lgkmcnt wait

  // weighted sum over m: quad q covers m in [q*16, q*16+16); lane handles
  // t = col*4 .. col*4+3 via ushort4 reads; quad partials shfl-combined.
  float o0 = 0.f, o1 = 0.f, o2 = 0.f, o3 = 0.f;
#pragma unroll
  for (int j = 0; j < 16; ++j) {
    int mm = quad * 16 + j;
    float p = probL[b_local][mm];
    ushort4 pv = *(const ushort4*)&Pb[mm * PROW + b_local * T_ + col * 4];
    o0 = fmaf(p, bf2f(pv.x), o0);
    o1 = fmaf(p, bf2f(pv.y), o1);
    o2 = fmaf(p, bf2f(pv.z), o2);
    o3 = fmaf(p, bf2f(pv.w), o3);
  }
  o0 += __shfl_xor(o0, 16); o0 += __shfl_xor(o0, 32);
  o1 += __shfl_xor(o1, 16); o1 += __shfl_xor(o1, 32);
  o2 += __shfl_xor(o2, 16); o2 += __shfl_xor(o2, 32);
  o3 += __shfl_xor(o3, 16); o3 += __shfl_xor(o3, 32);

  // LayerNorm over t (t = col*4 + r, replicated across quads)
  float mu = o0 + o1 + o2 + o3;
#pragma unroll
  for (int off = 1; off <= 8; off <<= 1) mu += __shfl_xor(mu, off);
  mu *= (1.0f / 64.0f);
  float d0 = o0 - mu, d1 = o1 - mu, d2 = o2 - mu, d3 = o3 - mu;
  float var = d0 * d0 + d1 * d1 + d2 * d2 + d3 * d3;
#pragma unroll
  for (int off = 1; off <= 8; off <<= 1) var += __shfl_xor(var, off);
  var *= (1.0f / 64.0f);
  float rstd = rsqrtf(var + 1e-5f);
  if (quad == 0) {
    float4 gb = *(const float4*)(gamma + col * 4);
    float4 bb = *(const float4*)(beta + col * 4);
    float4 res;
    res.x = d0 * rstd * gb.x + bb.x;
    res.y = d1 * rstd * gb.y + bb.y;
    res.z = d2 * rstd * gb.z + bb.z;
    res.w = d3 * rstd * gb.w + bb.w;
    *(float4*)(out + ((size_t)(g4 * 4 + b_local) * N_ + n) * T_ + col * 4) = res;
  }
}

// ---------------------------------------------------------------------------
// Workspace layout (bytes):
//   Wq2    [M][N][T][D]      bf16 : off 0,           33,554,432
//   priors [N][G32][M][8][T] bf16 : off 33,554,432,  67,108,864
//   xb2    [M][B][D]         bf16 : off 100,663,296,  4,194,304
//   LHn    [L][T]            bf16 : off 104,857,600,     16,384
// ---------------------------------------------------------------------------
extern "C" void kernel_launch(void* const* d_in, const int* in_sizes, int n_in,
                              void* d_out, int out_size, void* d_ws, size_t ws_size,
                              hipStream_t stream) {
  const float* x = (const float*)d_in[0];
  const float* rw = (const float*)d_in[1];
  const float* thr = (const float*)d_in[2];
  const float* leaves = (const float*)d_in[3];
  const float* gamma = (const float*)d_in[4];
  const float* beta = (const float*)d_in[5];
  float* out = (float*)d_out;

  char* ws = (char*)d_ws;
  unsigned short* wq2 = (unsigned short*)(ws);
  unsigned short* priors = (unsigned short*)(ws + 33554432);
  unsigned short* xb2 = (unsigned short*)(ws + 33554432 + 67108864);
  unsigned short* lhn = (unsigned short*)(ws + 33554432 + 67108864 + 4194304);

  hipLaunchKernelGGL(k_entmax, dim3(4097), dim3(256), 0, stream, rw, wq2, x, leaves, xb2, lhn);
  hipLaunchKernelGGL(k_priors, dim3(64, 32), dim3(256), 0, stream, xb2, wq2, priors);
  hipLaunchKernelGGL(k_route, dim3(32, 64), dim3(256), 0, stream, priors, lhn, thr, gamma, beta, out);
}

// Round 9
// 193.970 us; speedup vs baseline: 1.2272x; 1.0464x over previous
//
#include <hip/hip_runtime.h>
#include <hip/hip_bf16.h>
#include <math.h>

// Problem sizes (fixed by reference): B=256, M=64, N=32, D=128, T=64, L=128
#define B_ 256
#define M_ 64
#define N_ 32
#define D_ 128
#define T_ 64
#define L_ 128

typedef __attribute__((ext_vector_type(8))) short short8;   // 8 bf16 = 4 VGPRs (MFMA A/B frag)
typedef __attribute__((ext_vector_type(4))) float floatx4;  // MFMA C/D frag

__device__ __forceinline__ unsigned short f2bf(float f) {
  unsigned int u = __float_as_uint(f);
  unsigned int r = (u + 0x7fffu + ((u >> 16) & 1u)) >> 16;  // RNE
  return (unsigned short)r;
}
__device__ __forceinline__ float bf2f(unsigned short s) {
  return __uint_as_float(((unsigned int)s) << 16);
}
__device__ __forceinline__ float frcp(float x) { return __builtin_amdgcn_rcpf(x); }

// ---------------------------------------------------------------------------
// K1: exact entmax-1.5 over D of route_weights [M,N,D,T] (blocks < 2048),
// PLUS folded prep (blocks >= 2048): x -> bf16 transposed xb2[M][B][D],
// normalize leaves -> LHn bf16, transpose thr -> thrT[N][M] fp32.
// entmax: 4 threads/vector, 12 bisections (2 ILP chains) + exact solve.
// ---------------------------------------------------------------------------
__global__ __launch_bounds__(256) void k_entmax(const float* __restrict__ rw,
                                                unsigned short* __restrict__ wq2,
                                                const float* __restrict__ x,
                                                const float* __restrict__ leaves,
                                                unsigned short* __restrict__ xb2,
                                                unsigned short* __restrict__ lhn,
                                                const float* __restrict__ thr,
                                                float* __restrict__ thrT) {
  const int tid = threadIdx.x;
  if (blockIdx.x >= 2048) {  // prep paths
    int bid = blockIdx.x - 2048;
    if (bid < 2048) {
      size_t e = ((size_t)bid * 256 + tid) * 4;
      int b = (int)(e >> 13);        // / (M*D = 8192)
      int rem = (int)(e & 8191);
      int mm = rem >> 7, dd = rem & 127;
      float4 v = *(const float4*)(x + e);
      ushort4 o;
      o.x = f2bf(v.x); o.y = f2bf(v.y); o.z = f2bf(v.z); o.w = f2bf(v.w);
      *(ushort4*)(xb2 + ((size_t)mm * B_ + b) * D_ + dd) = o;
    } else if (bid == 2048) {
      if (tid < L_) {
        const float* r = leaves + tid * T_;
        float ss = 0.f;
        for (int i = 0; i < T_; ++i) ss = fmaf(r[i], r[i], ss);
        float inv = frcp(fmaxf(sqrtf(ss), 1e-12f));
        unsigned short* o = lhn + tid * T_;
        for (int i = 0; i < T_; ++i) o[i] = f2bf(r[i] * inv);
      }
    } else {  // thr transpose: thrT[n][m] = thr[m][n]
#pragma unroll
      for (int k = 0; k < 8; ++k) {
        int idx = k * 256 + tid;         // idx = n*64+m
        int nn = idx >> 6, mm = idx & 63;
        thrT[idx] = thr[mm * N_ + nn];
      }
    }
    return;
  }

  const int gv = blockIdx.x * 64 + (tid >> 2);  // vector id = (m*N+n)*T + t
  const int h = tid & 3;                        // quarter of D
  const int mn = gv >> 6;
  const int t = gv & 63;
  const float* base = rw + ((size_t)mn * D_ + h * 32) * T_ + t;
  float xv_[32];
#pragma unroll
  for (int i = 0; i < 32; ++i) xv_[i] = base[(size_t)i * T_];
  float mx = xv_[0];
#pragma unroll
  for (int i = 1; i < 32; ++i) mx = fmaxf(mx, xv_[i]);
  mx = fmaxf(mx, __shfl_xor(mx, 1));
  mx = fmaxf(mx, __shfl_xor(mx, 2));
#pragma unroll
  for (int i = 0; i < 32; ++i) xv_[i] = (xv_[i] - mx) * 0.5f;

  float lo = -1.0f, hi = 0.0f;
  for (int it = 0; it < 12; ++it) {
    float tau = 0.5f * (lo + hi);
    float f0 = 0.0f, f1 = 0.0f;  // 2 ILP chains
#pragma unroll
    for (int i = 0; i < 16; ++i) {
      float u0 = fmaxf(xv_[2 * i] - tau, 0.0f);
      float u1 = fmaxf(xv_[2 * i + 1] - tau, 0.0f);
      f0 = fmaf(u0, u0, f0);
      f1 = fmaf(u1, u1, f1);
    }
    float f = f0 + f1;
    f += __shfl_xor(f, 1);
    f += __shfl_xor(f, 2);
    if (f >= 1.0f) lo = tau; else hi = tau;
  }
  float tau0 = 0.5f * (lo + hi);
  float cnt = 0.f, s1 = 0.f, s2 = 0.f;
#pragma unroll
  for (int i = 0; i < 32; ++i) {
    bool in = xv_[i] > tau0;
    float q = in ? xv_[i] : 0.0f;
    cnt += in ? 1.0f : 0.0f;
    s1 += q;
    s2 = fmaf(q, q, s2);
  }
  cnt += __shfl_xor(cnt, 1); cnt += __shfl_xor(cnt, 2);
  s1 += __shfl_xor(s1, 1);   s1 += __shfl_xor(s1, 2);
  s2 += __shfl_xor(s2, 1);   s2 += __shfl_xor(s2, 2);
  float rc = frcp(cnt);
  float mean = s1 * rc;
  float ss = s2 - mean * s1;
  float delta = (1.0f - ss) * rc;
  float tau = mean - sqrtf(fmaxf(delta, 0.0f));

  unsigned short pv[32];
#pragma unroll
  for (int i = 0; i < 32; ++i) {
    float u = fmaxf(xv_[i] - tau, 0.0f);
    pv[i] = f2bf(u * u);
  }
  uint4* o = (uint4*)(wq2 + (size_t)gv * D_ + h * 32);
#pragma unroll
  for (int j = 0; j < 4; ++j) {
    uint4 w;
    w.x = (unsigned)pv[8 * j + 0] | ((unsigned)pv[8 * j + 1] << 16);
    w.y = (unsigned)pv[8 * j + 2] | ((unsigned)pv[8 * j + 3] << 16);
    w.z = (unsigned)pv[8 * j + 4] | ((unsigned)pv[8 * j + 5] << 16);
    w.w = (unsigned)pv[8 * j + 6] | ((unsigned)pv[8 * j + 7] << 16);
    o[j] = w;
  }
}

// ---------------------------------------------------------------------------
// K2: priors GEMM. ONE block per (m,n), all 256 b in 2 chunks of 128.
// R9: A-fragments read DIRECTLY from xb2 global (slab is L2-resident; same-m
// blocks land on the same XCD since they are 64 apart in block id). LDS only
// Bs (17KB) + Ct (18KB) -> 4 blocks/CU. Store priors[n][g8][m][bq][t].
// ---------------------------------------------------------------------------
#define BS_STRIDE 136
__global__ __launch_bounds__(256, 4) void k_priors(const unsigned short* __restrict__ xb2,
                                                   const unsigned short* __restrict__ wq2,
                                                   unsigned short* __restrict__ priors) {
  const int m = blockIdx.x, n = blockIdx.y;
  const int tid = threadIdx.x;
  const int wid = tid >> 6, lane = tid & 63;
  const int row16 = lane & 15, quad = lane >> 4;
  __shared__ __align__(16) unsigned short Bs[64 * BS_STRIDE];
  __shared__ __align__(16) unsigned short Ct[128 * 72];

  const unsigned short* bsrc = wq2 + ((size_t)(m * N_ + n) * T_) * D_;  // 64x128 contiguous
  {
    int tr = tid >> 4;
    int c = tid & 15;
#pragma unroll
    for (int p = 0; p < 4; ++p) {
      int row = p * 16 + tr;
      uint4 v = *(const uint4*)(bsrc + row * D_ + c * 8);
      *(uint4*)&Bs[row * BS_STRIDE + c * 8] = v;
    }
  }
  __syncthreads();

#pragma unroll
  for (int c = 0; c < 2; ++c) {  // chunk of 128 b
    short8 afr[2][4];
#pragma unroll
    for (int sc = 0; sc < 2; ++sc) {
      const int brow = c * 128 + wid * 32 + sc * 16 + row16;
      const unsigned short* aptr = xb2 + ((size_t)m * B_ + brow) * D_ + quad * 8;
#pragma unroll
      for (int ks = 0; ks < 4; ++ks) afr[sc][ks] = *(const short8*)(aptr + ks * 32);
    }

    floatx4 acc[2][4];
#pragma unroll
    for (int sc = 0; sc < 2; ++sc)
#pragma unroll
      for (int cf = 0; cf < 4; ++cf) acc[sc][cf] = (floatx4){0.f, 0.f, 0.f, 0.f};

#pragma unroll
    for (int cf = 0; cf < 4; ++cf) {
#pragma unroll
      for (int ks = 0; ks < 4; ++ks) {
        short8 bfr = *(const short8*)&Bs[(cf * 16 + row16) * BS_STRIDE + ks * 32 + quad * 8];
#pragma unroll
        for (int sc = 0; sc < 2; ++sc)
          acc[sc][cf] = __builtin_amdgcn_mfma_f32_16x16x32_bf16(afr[sc][ks], bfr, acc[sc][cf], 0, 0, 0);
      }
    }

    if (c) __syncthreads();  // chunk-0 stores (reading Ct) must finish first
#pragma unroll
    for (int sc = 0; sc < 2; ++sc)
#pragma unroll
      for (int cf = 0; cf < 4; ++cf)
#pragma unroll
        for (int r = 0; r < 4; ++r)
          Ct[(wid * 32 + sc * 16 + quad * 4 + r) * 72 + cf * 16 + row16] = f2bf(acc[sc][cf][r]);
    __syncthreads();

    {  // store 128 rows x 128B; 16 lanes = one 1KB contiguous chunk
      int q = tid >> 4, s = tid & 15;
      int row = q * 8 + (s >> 1);
      int half = s & 1;
      const unsigned short* src = &Ct[row * 72 + half * 32];
      unsigned short* dst = priors +
          ((((size_t)n * 32 + c * 16 + q) * M_ + m) * 8 + (s >> 1)) * T_ + half * 32;
      uint4 a0 = *(const uint4*)(src);
      uint4 a1 = *(const uint4*)(src + 8);
      uint4 a2 = *(const uint4*)(src + 16);
      uint4 a3 = *(const uint4*)(src + 24);
      *(uint4*)(dst) = a0;
      *(uint4*)(dst + 8) = a1;
      *(uint4*)(dst + 16) = a2;
      *(uint4*)(dst + 24) = a3;
    }
  }
}

// ---------------------------------------------------------------------------
// K3 (R9 rewrite): block = (n, g4); wave owns ONE b. NO LDS staging, NO
// barriers. afr A-frags read directly from the contiguous priors slab
// (global/L2); votes in 4 l-slices of 32 (acc 32 VGPR, peak ~95 regs);
// sigmoid/softmax use v_rcp (was full-precision divide: ~10 inst each — the
// R3-R8 VALU bottleneck); weighted sum reuses afr registers (t = k index);
// thr via thrT coalesced load + shfl; prob redistribution via 1KB same-wave
// LDS. LN via shfl over quad bits.
// ---------------------------------------------------------------------------
__global__ __launch_bounds__(256, 4) void k_route(const unsigned short* __restrict__ priors,
                                                  const unsigned short* __restrict__ lhn,
                                                  const float* __restrict__ thrT,
                                                  const float* __restrict__ gamma,
                                                  const float* __restrict__ beta,
                                                  float* __restrict__ out) {
  const int n = blockIdx.x, g4 = blockIdx.y;
  const int tid = threadIdx.x;
  const int wid = tid >> 6, lane = tid & 63;
  const int col = lane & 15, quad = lane >> 4;

  __shared__ float probL[4][64];

  const int g = g4 >> 1;
  const int bq = (g4 & 1) * 4 + wid;  // position within the g8 slab

  const unsigned short* base = priors + (((size_t)n * 32 + g) * M_) * 512 + bq * T_;
  short8 afr[4][2];  // A[m = mt*16+col][k(t) = ks*32+quad*8+j]
#pragma unroll
  for (int mt = 0; mt < 4; ++mt)
#pragma unroll
    for (int ks = 0; ks < 2; ++ks)
      afr[mt][ks] = *(const short8*)(base + (size_t)(mt * 16 + col) * 512 + ks * 32 + quad * 8);

  float thv = thrT[n * 64 + lane];  // coalesced; redistributed via shfl below

  float dis[4][4];
#pragma unroll
  for (int mt = 0; mt < 4; ++mt)
#pragma unroll
    for (int r = 0; r < 4; ++r) dis[mt][r] = 0.f;

#pragma unroll
  for (int s4 = 0; s4 < 4; ++s4) {  // l-slice of 32
    floatx4 acc[4][2];  // C[m = mt*16+quad*4+r][l = s4*32+lt*16+col]
#pragma unroll
    for (int mt = 0; mt < 4; ++mt)
#pragma unroll
      for (int lt = 0; lt < 2; ++lt) acc[mt][lt] = (floatx4){0.f, 0.f, 0.f, 0.f};

#pragma unroll
    for (int lt = 0; lt < 2; ++lt) {
#pragma unroll
      for (int ks = 0; ks < 2; ++ks) {
        short8 bfr = *(const short8*)(lhn + (s4 * 32 + lt * 16 + col) * T_ + ks * 32 + quad * 8);
#pragma unroll
        for (int mt = 0; mt < 4; ++mt)
          acc[mt][lt] = __builtin_amdgcn_mfma_f32_16x16x32_bf16(afr[mt][ks], bfr, acc[mt][lt], 0, 0, 0);
      }
    }

    // sigmoid via v_rcp (NOT full-precision divide)
#pragma unroll
    for (int mt = 0; mt < 4; ++mt)
#pragma unroll
      for (int lt = 0; lt < 2; ++lt)
#pragma unroll
        for (int r = 0; r < 4; ++r)
          acc[mt][lt][r] = frcp(1.0f + __expf(-acc[mt][lt][r]));

    float mc[2];
#pragma unroll
    for (int lt = 0; lt < 2; ++lt) {
      float s = 0.f;
#pragma unroll
      for (int mt = 0; mt < 4; ++mt)
#pragma unroll
        for (int r = 0; r < 4; ++r) s += acc[mt][lt][r];
      s += __shfl_xor(s, 16);
      s += __shfl_xor(s, 32);
      mc[lt] = s * (1.0f / 64.0f);
    }

#pragma unroll
    for (int mt = 0; mt < 4; ++mt)
#pragma unroll
      for (int r = 0; r < 4; ++r) {
        float s = 0.f;
#pragma unroll
        for (int lt = 0; lt < 2; ++lt) {
          float df = acc[mt][lt][r] - mc[lt];
          s = fmaf(df, df, s);
        }
        dis[mt][r] += s;
      }
  }

  // butterfly over col bits -> dis[m] summed over all 128 l (replicated)
#pragma unroll
  for (int off = 1; off <= 8; off <<= 1)
#pragma unroll
    for (int mt = 0; mt < 4; ++mt)
#pragma unroll
      for (int r = 0; r < 4; ++r) dis[mt][r] += __shfl_xor(dis[mt][r], off);

  // weight + softmax over m (m = mt*16 + quad*4 + r); w >= 0 so mxw init 0
  float e[4][4];
  float mxw = 0.f;
#pragma unroll
  for (int mt = 0; mt < 4; ++mt)
#pragma unroll
    for (int r = 0; r < 4; ++r) {
      float th = __shfl(thv, mt * 16 + quad * 4 + r);
      float w = fmaxf(th * th - dis[mt][r] * (1.0f / 128.0f), 0.0f);
      e[mt][r] = w;
      mxw = fmaxf(mxw, w);
    }
  mxw = fmaxf(mxw, __shfl_xor(mxw, 16));
  mxw = fmaxf(mxw, __shfl_xor(mxw, 32));
  float ssum = 0.f;
#pragma unroll
  for (int mt = 0; mt < 4; ++mt)
#pragma unroll
    for (int r = 0; r < 4; ++r) {
      e[mt][r] = __expf(e[mt][r] - mxw);
      ssum += e[mt][r];
    }
  ssum += __shfl_xor(ssum, 16);
  ssum += __shfl_xor(ssum, 32);
  float inv = frcp(ssum);
  if (col == 0) {
#pragma unroll
    for (int mt = 0; mt < 4; ++mt)
#pragma unroll
      for (int r = 0; r < 4; ++r)
        probL[wid][mt * 16 + quad * 4 + r] = e[mt][r] * inv;
  }
  // same-wave LDS write->read: compiler inserts lgkmcnt wait (no barrier)

  float pr[4];
#pragma unroll
  for (int mt = 0; mt < 4; ++mt) pr[mt] = probL[wid][mt * 16 + col];

  // weighted sum over m REUSING afr: t = ks*32 + quad*8 + j
  float o[2][8];
#pragma unroll
  for (int ks = 0; ks < 2; ++ks)
#pragma unroll
    for (int j = 0; j < 8; ++j) o[ks][j] = 0.f;
#pragma unroll
  for (int mt = 0; mt < 4; ++mt)
#pragma unroll
    for (int ks = 0; ks < 2; ++ks)
#pragma unroll
      for (int j = 0; j < 8; ++j)
        o[ks][j] = fmaf(pr[mt], bf2f((unsigned short)afr[mt][ks][j]), o[ks][j]);
  // reduce over col bits (16 lanes hold partial m-sets)
#pragma unroll
  for (int off = 1; off <= 8; off <<= 1)
#pragma unroll
    for (int ks = 0; ks < 2; ++ks)
#pragma unroll
      for (int j = 0; j < 8; ++j) o[ks][j] += __shfl_xor(o[ks][j], off);

  // LayerNorm over t: 16 regs/lane + shfl over quad bits
  float mu = 0.f;
#pragma unroll
  for (int ks = 0; ks < 2; ++ks)
#pragma unroll
    for (int j = 0; j < 8; ++j) mu += o[ks][j];
  mu += __shfl_xor(mu, 16);
  mu += __shfl_xor(mu, 32);
  mu *= (1.0f / 64.0f);
  float var = 0.f;
#pragma unroll
  for (int ks = 0; ks < 2; ++ks)
#pragma unroll
    for (int j = 0; j < 8; ++j) {
      float d = o[ks][j] - mu;
      o[ks][j] = d;
      var = fmaf(d, d, var);
    }
  var += __shfl_xor(var, 16);
  var += __shfl_xor(var, 32);
  var *= (1.0f / 64.0f);
  float rstd = rsqrtf(var + 1e-5f);

  if (col == 0) {
    const int b = g4 * 4 + wid;
    float* obase = out + ((size_t)b * N_ + n) * T_;
#pragma unroll
    for (int ks = 0; ks < 2; ++ks) {
      int tb = ks * 32 + quad * 8;
      float4 g0 = *(const float4*)(gamma + tb);
      float4 g1 = *(const float4*)(gamma + tb + 4);
      float4 b0 = *(const float4*)(beta + tb);
      float4 b1 = *(const float4*)(beta + tb + 4);
      float4 r0, r1;
      r0.x = o[ks][0] * rstd * g0.x + b0.x;
      r0.y = o[ks][1] * rstd * g0.y + b0.y;
      r0.z = o[ks][2] * rstd * g0.z + b0.z;
      r0.w = o[ks][3] * rstd * g0.w + b0.w;
      r1.x = o[ks][4] * rstd * g1.x + b1.x;
      r1.y = o[ks][5] * rstd * g1.y + b1.y;
      r1.z = o[ks][6] * rstd * g1.z + b1.z;
      r1.w = o[ks][7] * rstd * g1.w + b1.w;
      *(float4*)(obase + tb) = r0;
      *(float4*)(obase + tb + 4) = r1;
    }
  }
}

// ---------------------------------------------------------------------------
// Workspace layout (bytes):
//   Wq2    [M][N][T][D]      bf16 : off 0,           33,554,432
//   priors [N][G32][M][8][T] bf16 : off 33,554,432,  67,108,864
//   xb2    [M][B][D]         bf16 : off 100,663,296,  4,194,304
//   LHn    [L][T]            bf16 : off 104,857,600,     16,384
//   thrT   [N][M]            fp32 : off 104,873,984,      8,192
// ---------------------------------------------------------------------------
extern "C" void kernel_launch(void* const* d_in, const int* in_sizes, int n_in,
                              void* d_out, int out_size, void* d_ws, size_t ws_size,
                              hipStream_t stream) {
  const float* x = (const float*)d_in[0];
  const float* rw = (const float*)d_in[1];
  const float* thr = (const float*)d_in[2];
  const float* leaves = (const float*)d_in[3];
  const float* gamma = (const float*)d_in[4];
  const float* beta = (const float*)d_in[5];
  float* out = (float*)d_out;

  char* ws = (char*)d_ws;
  unsigned short* wq2 = (unsigned short*)(ws);
  unsigned short* priors = (unsigned short*)(ws + 33554432);
  unsigned short* xb2 = (unsigned short*)(ws + 33554432 + 67108864);
  unsigned short* lhn = (unsigned short*)(ws + 100663296 + 4194304);
  float* thrT = (float*)(ws + 104857600 + 16384);

  hipLaunchKernelGGL(k_entmax, dim3(4098), dim3(256), 0, stream, rw, wq2, x, leaves, xb2, lhn, thr, thrT);
  hipLaunchKernelGGL(k_priors, dim3(64, 32), dim3(256), 0, stream, xb2, wq2, priors);
  hipLaunchKernelGGL(k_route, dim3(32, 64), dim3(256), 0, stream, priors, lhn, thrT, gamma, beta, out);
}